// Round 1
// baseline (351.473 us; speedup 1.0000x reference)
//
#include <hip/hip_runtime.h>
#include <hip/hip_bf16.h>

typedef __bf16 bf16;
typedef __attribute__((ext_vector_type(8))) __bf16 bf16x8;
typedef __attribute__((ext_vector_type(4))) __bf16 bf16x4;
typedef __attribute__((ext_vector_type(4))) float f32x4;

// ---------------------------------------------------------------------------
// GEMM: C[M,N] = A[M,K] @ Bt[N,K]^T + bias  (einsum 'md,nd->mn')
// A is fp32 (A_BF16=false) or bf16 (true). Bt/bias always fp32.
// OUT_QKV=true: write bf16 into [B=2,H=16,S=2048,hd=64] layout.
// OUT_QKV=false: write fp32 row-major [M,N].
// M=4096, N=1024, K=1024 hardcoded.
// ---------------------------------------------------------------------------
template <bool A_BF16, bool OUT_QKV>
__global__ __launch_bounds__(256) void gemm_bt_kernel(
    const void* __restrict__ Aptr, const float* __restrict__ Bt,
    const float* __restrict__ bias, void* __restrict__ Cptr) {
  constexpr int K = 1024, N = 1024;
  constexpr int BM = 128, BK = 32;
  constexpr int LSTR = BK + 8;  // 40 elems = 80B: 2-way-free bank pattern, 16B-aligned rows
  __shared__ bf16 As[BM][LSTR];
  __shared__ bf16 Bs[BM][LSTR];

  const int tid = threadIdx.x;
  const int lane = tid & 63;
  const int w = tid >> 6;
  const int wr = w >> 1, wc = w & 1;
  const int g = lane >> 4, c16 = lane & 15;
  const int row0 = blockIdx.y * BM;
  const int col0 = blockIdx.x * BM;

  f32x4 acc[4][4] = {};

  for (int kt = 0; kt < K / BK; ++kt) {
    const int k0 = kt * BK;
    // ---- stage A tile (128 x 32) ----
    if constexpr (!A_BF16) {
      const float* A = (const float*)Aptr;
#pragma unroll
      for (int i = 0; i < 4; ++i) {
        const int r = (tid >> 3) + i * 32;
        const int c = (tid & 7) * 4;
        const float4 v = *(const float4*)(&A[(size_t)(row0 + r) * K + k0 + c]);
        bf16x4 hv;
        hv[0] = (bf16)v.x; hv[1] = (bf16)v.y; hv[2] = (bf16)v.z; hv[3] = (bf16)v.w;
        *(bf16x4*)&As[r][c] = hv;
      }
    } else {
      const bf16* A = (const bf16*)Aptr;
#pragma unroll
      for (int i = 0; i < 2; ++i) {
        const int r = (tid >> 2) + i * 64;
        const int c = (tid & 3) * 8;
        *(bf16x8*)&As[r][c] = *(const bf16x8*)(&A[(size_t)(row0 + r) * K + k0 + c]);
      }
    }
    // ---- stage B tile (128 x 32) from fp32 weights ----
#pragma unroll
    for (int i = 0; i < 4; ++i) {
      const int r = (tid >> 3) + i * 32;
      const int c = (tid & 7) * 4;
      const float4 v = *(const float4*)(&Bt[(size_t)(col0 + r) * K + k0 + c]);
      bf16x4 hv;
      hv[0] = (bf16)v.x; hv[1] = (bf16)v.y; hv[2] = (bf16)v.z; hv[3] = (bf16)v.w;
      *(bf16x4*)&Bs[r][c] = hv;
    }
    __syncthreads();

    bf16x8 a[4], b[4];
#pragma unroll
    for (int m = 0; m < 4; ++m)
      a[m] = *(bf16x8*)&As[wr * 64 + m * 16 + c16][g * 8];
#pragma unroll
    for (int n = 0; n < 4; ++n)
      b[n] = *(bf16x8*)&Bs[wc * 64 + n * 16 + c16][g * 8];
#pragma unroll
    for (int m = 0; m < 4; ++m)
#pragma unroll
      for (int n = 0; n < 4; ++n)
        acc[m][n] = __builtin_amdgcn_mfma_f32_16x16x32_bf16(a[m], b[n], acc[m][n], 0, 0, 0);
    __syncthreads();
  }

  // ---- epilogue ----
#pragma unroll
  for (int m = 0; m < 4; ++m) {
#pragma unroll
    for (int n = 0; n < 4; ++n) {
#pragma unroll
      for (int r = 0; r < 4; ++r) {
        const int row = row0 + wr * 64 + m * 16 + g * 4 + r;
        const int col = col0 + wc * 64 + n * 16 + c16;
        const float v = acc[m][n][r] + bias[col];
        if constexpr (OUT_QKV) {
          const int bb = row >> 11, s = row & 2047;
          const int hh = col >> 6, j = col & 63;
          ((bf16*)Cptr)[(((size_t)bb * 16 + hh) * 2048 + s) * 64 + j] = (bf16)v;
        } else {
          ((float*)Cptr)[(size_t)row * N + col] = v;
        }
      }
    }
  }
}

// ---------------------------------------------------------------------------
// Causal flash attention. Q/K/V bf16 [B=2,H=16,S=2048,hd=64] -> ctx bf16
// [B,S,1024] (head-concat layout). Q prescaled by 1/sqrt(64) at load.
// Block: 256 threads = 4 waves; workgroup = 128 q-rows (32 per wave);
// KV tiles of 32 staged in LDS.
// ---------------------------------------------------------------------------
__global__ __launch_bounds__(256) void attn_kernel(
    const bf16* __restrict__ Q, const bf16* __restrict__ Kb,
    const bf16* __restrict__ Vb, bf16* __restrict__ ctx) {
  constexpr int S = 2048, HD = 64;
  constexpr int KLDS = HD + 8;  // 72
  constexpr int VLDS = 32 + 8;  // 40
  __shared__ bf16 Ks[32][KLDS];
  __shared__ bf16 Vt[HD][VLDS];
  __shared__ bf16 Ps[4][32][VLDS];

  const int tid = threadIdx.x;
  const int lane = tid & 63;
  const int w = tid >> 6;
  const int g = lane >> 4, c16 = lane & 15;
  const int qt = blockIdx.x, bh = blockIdx.y;
  const int b = bh >> 4, h = bh & 15;

  const size_t base = (size_t)bh * S * HD;
  const bf16* Qh = Q + base;
  const bf16* Kh = Kb + base;
  const bf16* Vh = Vb + base;

  const int q0 = qt * 128 + w * 32;

  // Q fragments in registers, prescaled
  bf16x8 qf[2][2];
#pragma unroll
  for (int mi = 0; mi < 2; ++mi)
#pragma unroll
    for (int ks = 0; ks < 2; ++ks) {
      bf16x8 t = *(const bf16x8*)&Qh[(size_t)(q0 + mi * 16 + c16) * HD + ks * 32 + g * 8];
#pragma unroll
      for (int e = 0; e < 8; ++e) t[e] = (bf16)((float)t[e] * 0.125f);
      qf[mi][ks] = t;
    }

  f32x4 oacc[2][4] = {};
  float mrun[2][4], lrun[2][4];
#pragma unroll
  for (int mi = 0; mi < 2; ++mi)
#pragma unroll
    for (int r = 0; r < 4; ++r) { mrun[mi][r] = -1e30f; lrun[mi][r] = 0.f; }

  const int ktiles = 4 * qt + 4;
  for (int kt = 0; kt < ktiles; ++kt) {
    const int kv0 = kt * 32;
    // ---- stage K (32x64) and V^T (64x32) ----
    {
      const int r = tid >> 3;
      const int c = (tid & 7) * 8;
      *(bf16x8*)&Ks[r][c] = *(const bf16x8*)&Kh[(size_t)(kv0 + r) * HD + c];
      const bf16x8 v = *(const bf16x8*)&Vh[(size_t)(kv0 + r) * HD + c];
#pragma unroll
      for (int e = 0; e < 8; ++e) Vt[c + e][r] = v[e];
    }
    __syncthreads();

    // ---- S = Q K^T (per wave: 32 q-rows x 32 kv-cols) ----
    f32x4 sc[2][2] = {};
    bf16x8 kf[2][2];
#pragma unroll
    for (int ni = 0; ni < 2; ++ni)
#pragma unroll
      for (int ks = 0; ks < 2; ++ks)
        kf[ni][ks] = *(bf16x8*)&Ks[ni * 16 + c16][ks * 32 + g * 8];
#pragma unroll
    for (int mi = 0; mi < 2; ++mi)
#pragma unroll
      for (int ni = 0; ni < 2; ++ni)
#pragma unroll
        for (int ks = 0; ks < 2; ++ks)
          sc[mi][ni] = __builtin_amdgcn_mfma_f32_16x16x32_bf16(qf[mi][ks], kf[ni][ks], sc[mi][ni], 0, 0, 0);

    // ---- causal mask ----
#pragma unroll
    for (int mi = 0; mi < 2; ++mi)
#pragma unroll
      for (int ni = 0; ni < 2; ++ni)
#pragma unroll
        for (int r = 0; r < 4; ++r) {
          const int kv = kv0 + ni * 16 + c16;
          const int qq = q0 + mi * 16 + g * 4 + r;
          if (kv > qq) sc[mi][ni][r] = -1e30f;
        }

    // ---- online softmax ----
    float corr[2][4];
#pragma unroll
    for (int mi = 0; mi < 2; ++mi)
#pragma unroll
      for (int r = 0; r < 4; ++r) {
        float t = fmaxf(sc[mi][0][r], sc[mi][1][r]);
        t = fmaxf(t, __shfl_xor(t, 1));
        t = fmaxf(t, __shfl_xor(t, 2));
        t = fmaxf(t, __shfl_xor(t, 4));
        t = fmaxf(t, __shfl_xor(t, 8));
        const float mnew = fmaxf(mrun[mi][r], t);
        corr[mi][r] = __expf(mrun[mi][r] - mnew);
        mrun[mi][r] = mnew;
      }
#pragma unroll
    for (int mi = 0; mi < 2; ++mi)
#pragma unroll
      for (int ni = 0; ni < 2; ++ni)
#pragma unroll
        for (int r = 0; r < 4; ++r)
          sc[mi][ni][r] = __expf(sc[mi][ni][r] - mrun[mi][r]);
#pragma unroll
    for (int mi = 0; mi < 2; ++mi)
#pragma unroll
      for (int r = 0; r < 4; ++r) {
        float rs = sc[mi][0][r] + sc[mi][1][r];
        rs += __shfl_xor(rs, 1);
        rs += __shfl_xor(rs, 2);
        rs += __shfl_xor(rs, 4);
        rs += __shfl_xor(rs, 8);
        lrun[mi][r] = lrun[mi][r] * corr[mi][r] + rs;
      }

    // ---- P -> LDS (D-layout -> A-fragment layout round trip) ----
#pragma unroll
    for (int mi = 0; mi < 2; ++mi)
#pragma unroll
      for (int ni = 0; ni < 2; ++ni)
#pragma unroll
        for (int r = 0; r < 4; ++r)
          Ps[w][mi * 16 + g * 4 + r][ni * 16 + c16] = (bf16)sc[mi][ni][r];
    asm volatile("s_waitcnt lgkmcnt(0)" ::: "memory");

    // ---- rescale O ----
#pragma unroll
    for (int mi = 0; mi < 2; ++mi)
#pragma unroll
      for (int nd = 0; nd < 4; ++nd)
#pragma unroll
        for (int r = 0; r < 4; ++r) oacc[mi][nd][r] *= corr[mi][r];

    // ---- O += P V ----
    bf16x8 pa[2], bv[4];
#pragma unroll
    for (int mi = 0; mi < 2; ++mi)
      pa[mi] = *(bf16x8*)&Ps[w][mi * 16 + c16][g * 8];
#pragma unroll
    for (int nd = 0; nd < 4; ++nd)
      bv[nd] = *(bf16x8*)&Vt[nd * 16 + c16][g * 8];
#pragma unroll
    for (int mi = 0; mi < 2; ++mi)
#pragma unroll
      for (int nd = 0; nd < 4; ++nd)
        oacc[mi][nd] = __builtin_amdgcn_mfma_f32_16x16x32_bf16(pa[mi], bv[nd], oacc[mi][nd], 0, 0, 0);

    __syncthreads();
  }

  // ---- epilogue: normalize and write ctx[b, s, h*64+d] ----
#pragma unroll
  for (int mi = 0; mi < 2; ++mi)
#pragma unroll
    for (int nd = 0; nd < 4; ++nd)
#pragma unroll
      for (int r = 0; r < 4; ++r) {
        const int srow = q0 + mi * 16 + g * 4 + r;
        const int col = h * 64 + nd * 16 + c16;
        const float ov = oacc[mi][nd][r] / lrun[mi][r];
        ctx[((size_t)b * 2048 + srow) * 1024 + col] = (bf16)ov;
      }
}

// ---------------------------------------------------------------------------
extern "C" void kernel_launch(void* const* d_in, const int* in_sizes, int n_in,
                              void* d_out, int out_size, void* d_ws, size_t ws_size,
                              hipStream_t stream) {
  (void)in_sizes; (void)n_in; (void)out_size; (void)ws_size;
  const float* query = (const float*)d_in[0];
  const float* key   = (const float*)d_in[1];
  const float* value = (const float*)d_in[2];
  // d_in[3] = attn_mask (causal triu, k=1) — structural, not read
  const float* q_w = (const float*)d_in[4];
  const float* q_b = (const float*)d_in[5];
  const float* k_w = (const float*)d_in[6];
  const float* k_b = (const float*)d_in[7];
  const float* v_w = (const float*)d_in[8];
  const float* v_b = (const float*)d_in[9];
  const float* o_w = (const float*)d_in[10];
  const float* o_b = (const float*)d_in[11];

  const size_t NELEM = (size_t)4096 * 1024;  // B*S*D
  bf16* Qbuf = (bf16*)d_ws;
  bf16* Kbuf = Qbuf + NELEM;
  bf16* Vbuf = Kbuf + NELEM;
  bf16* ctxb = Vbuf + NELEM;

  const dim3 blk(256);
  const dim3 ggrid(8, 32);  // N-tiles x M-tiles

  gemm_bt_kernel<false, true><<<ggrid, blk, 0, stream>>>(query, q_w, q_b, Qbuf);
  gemm_bt_kernel<false, true><<<ggrid, blk, 0, stream>>>(key, k_w, k_b, Kbuf);
  gemm_bt_kernel<false, true><<<ggrid, blk, 0, stream>>>(value, v_w, v_b, Vbuf);

  attn_kernel<<<dim3(16, 32), blk, 0, stream>>>(Qbuf, Kbuf, Vbuf, ctxb);

  gemm_bt_kernel<true, false><<<ggrid, blk, 0, stream>>>(ctxb, o_w, o_b, (float*)d_out);
}

// Round 3
// 212.834 us; speedup vs baseline: 1.6514x; 1.6514x over previous
//
#include <hip/hip_runtime.h>
#include <hip/hip_bf16.h>

typedef __bf16 bf16;
typedef __attribute__((ext_vector_type(8))) __bf16 bf16x8;
typedef __attribute__((ext_vector_type(4))) __bf16 bf16x4;
typedef __attribute__((ext_vector_type(4))) float f32x4;

// ---------------------------------------------------------------------------
// GEMM: C[M,N] = (A[M,K] @ Bt[N,K]^T + bias) * scale  (einsum 'md,nd->mn')
// A fp32 (A_BF16=false) or bf16 (true). Bt/bias fp32.
// OUT_MODE 0: fp32 row-major [M,N]
// OUT_MODE 1: bf16 [B=2,H=16,S=2048,hd=64]   (Q, K)
// OUT_MODE 2: bf16 [B=2,H=16,hd=64,S=2048]   (V transposed)
// M=4096, N=1024, K=1024 hardcoded.
// ---------------------------------------------------------------------------
template <bool A_BF16, int OUT_MODE>
__global__ __launch_bounds__(256) void gemm_bt_kernel(
    const void* __restrict__ Aptr, const float* __restrict__ Bt,
    const float* __restrict__ bias, void* __restrict__ Cptr, float scale) {
  constexpr int K = 1024, N = 1024;
  constexpr int BM = 128, BK = 32;
  constexpr int LSTR = BK + 8;
  __shared__ __align__(16) bf16 As[BM][LSTR];
  __shared__ __align__(16) bf16 Bs[BM][LSTR];

  const int tid = threadIdx.x;
  const int lane = tid & 63;
  const int w = tid >> 6;
  const int wr = w >> 1, wc = w & 1;
  const int g = lane >> 4, c16 = lane & 15;
  const int row0 = blockIdx.y * BM;
  const int col0 = blockIdx.x * BM;

  f32x4 acc[4][4] = {};

  for (int kt = 0; kt < K / BK; ++kt) {
    const int k0 = kt * BK;
    if constexpr (!A_BF16) {
      const float* A = (const float*)Aptr;
#pragma unroll
      for (int i = 0; i < 4; ++i) {
        const int r = (tid >> 3) + i * 32;
        const int c = (tid & 7) * 4;
        const float4 v = *(const float4*)(&A[(size_t)(row0 + r) * K + k0 + c]);
        bf16x4 hv;
        hv[0] = (bf16)v.x; hv[1] = (bf16)v.y; hv[2] = (bf16)v.z; hv[3] = (bf16)v.w;
        *(bf16x4*)&As[r][c] = hv;
      }
    } else {
      const bf16* A = (const bf16*)Aptr;
#pragma unroll
      for (int i = 0; i < 2; ++i) {
        const int r = (tid >> 2) + i * 64;
        const int c = (tid & 3) * 8;
        *(bf16x8*)&As[r][c] = *(const bf16x8*)(&A[(size_t)(row0 + r) * K + k0 + c]);
      }
    }
#pragma unroll
    for (int i = 0; i < 4; ++i) {
      const int r = (tid >> 3) + i * 32;
      const int c = (tid & 7) * 4;
      const float4 v = *(const float4*)(&Bt[(size_t)(col0 + r) * K + k0 + c]);
      bf16x4 hv;
      hv[0] = (bf16)v.x; hv[1] = (bf16)v.y; hv[2] = (bf16)v.z; hv[3] = (bf16)v.w;
      *(bf16x4*)&Bs[r][c] = hv;
    }
    __syncthreads();

    bf16x8 a[4], b[4];
#pragma unroll
    for (int m = 0; m < 4; ++m)
      a[m] = *(bf16x8*)&As[wr * 64 + m * 16 + c16][g * 8];
#pragma unroll
    for (int n = 0; n < 4; ++n)
      b[n] = *(bf16x8*)&Bs[wc * 64 + n * 16 + c16][g * 8];
#pragma unroll
    for (int m = 0; m < 4; ++m)
#pragma unroll
      for (int n = 0; n < 4; ++n)
        acc[m][n] = __builtin_amdgcn_mfma_f32_16x16x32_bf16(a[m], b[n], acc[m][n], 0, 0, 0);
    __syncthreads();
  }

#pragma unroll
  for (int m = 0; m < 4; ++m) {
#pragma unroll
    for (int n = 0; n < 4; ++n) {
      const int col = col0 + wc * 64 + n * 16 + c16;
      if constexpr (OUT_MODE == 2) {
        const int row = row0 + wr * 64 + m * 16 + g * 4;  // s base, mult of 4
        const int bb = row >> 11, s = row & 2047;
        const int hh = col >> 6, j = col & 63;
        bf16x4 hv;
#pragma unroll
        for (int r = 0; r < 4; ++r)
          hv[r] = (bf16)((acc[m][n][r] + bias[col]) * scale);
        *(bf16x4*)&((bf16*)Cptr)[(((size_t)bb * 16 + hh) * 64 + j) * 2048 + s] = hv;
      } else {
#pragma unroll
        for (int r = 0; r < 4; ++r) {
          const int row = row0 + wr * 64 + m * 16 + g * 4 + r;
          const float v = (acc[m][n][r] + bias[col]) * scale;
          if constexpr (OUT_MODE == 1) {
            const int bb = row >> 11, s = row & 2047;
            const int hh = col >> 6, j = col & 63;
            ((bf16*)Cptr)[(((size_t)bb * 16 + hh) * 2048 + s) * 64 + j] = (bf16)v;
          } else {
            ((float*)Cptr)[(size_t)row * N + col] = v;
          }
        }
      }
    }
  }
}

// ---------------------------------------------------------------------------
// Causal flash attention, swapped-QK^T form.
// Q,K bf16 [B=2,H=16,S=2048,hd=64]; V bf16 [B,H,hd=64,S=2048] (pre-transposed).
// Q arrives pre-scaled by 0.125*log2(e) (folded into Q projection) -> exp2 softmax.
// Block: 256 thr = 4 waves; each wave owns 16 q-rows; block q-tile = 64 rows.
// Causal pairing: block processes q-tile j then 31-j  -> 33 KV tiles of 64 each.
// Double-buffered K/V staging, 1 barrier per tile, loads issued before compute.
// ---------------------------------------------------------------------------
__global__ __launch_bounds__(256) void attn_kernel(
    const bf16* __restrict__ Q, const bf16* __restrict__ Kb,
    const bf16* __restrict__ Vt, bf16* __restrict__ ctx) {
  constexpr int S = 2048, HD = 64, KVB = 64;
  constexpr int PS = 72;  // padded stride (144B rows, 16B aligned)
  __shared__ __align__(16) bf16 Ks[2][KVB][PS];
  __shared__ __align__(16) bf16 Vs[2][HD][PS];
  __shared__ __align__(16) bf16 PT[4][16][PS];

  const int tid = threadIdx.x;
  const int lane = tid & 63;
  const int w = tid >> 6;
  const int g = lane >> 4, c16 = lane & 15;
  const int bh = blockIdx.x;  // 0..31 -> XCD = bh%8 (K/V L2 locality)
  const int pj = blockIdx.y;  // 0..15 pair index
  const int b = bh >> 4, h = bh & 15;

  const bf16* Qh = Q + (size_t)bh * S * HD;
  const bf16* Kh = Kb + (size_t)bh * S * HD;
  const bf16* Vh = Vt + (size_t)bh * HD * S;  // [HD][S]

  const int srow = tid >> 2;        // 0..63 staging row
  const int scol = (tid & 3) * 16;  // staging col (elems)

#pragma unroll 1
  for (int phase = 0; phase < 2; ++phase) {
    const int qt = (phase == 0) ? pj : 31 - pj;
    const int q0w = qt * 64 + w * 16;  // wave's first q row
    const int nt = qt + 1;             // KV tiles needed

    // Q as B-fragment: lane holds Q[q0w+c16][ks*32+g*8 ..+7]
    bf16x8 qf[2];
#pragma unroll
    for (int ks = 0; ks < 2; ++ks)
      qf[ks] = *(const bf16x8*)&Qh[(size_t)(q0w + c16) * HD + ks * 32 + g * 8];

    f32x4 oacc[4] = {};          // PV acc: d = nd*16+c16, q = q0w+g*4+r
    float m = -1e30f, l = 0.f;   // softmax stats for q = q0w+c16 (log2 domain)

    // prologue: stage tile 0
    bf16x8 kr0 = *(const bf16x8*)&Kh[(size_t)srow * HD + scol];
    bf16x8 kr1 = *(const bf16x8*)&Kh[(size_t)srow * HD + scol + 8];
    bf16x8 vr0 = *(const bf16x8*)&Vh[(size_t)srow * S + scol];
    bf16x8 vr1 = *(const bf16x8*)&Vh[(size_t)srow * S + scol + 8];
    __syncthreads();  // previous phase readers done
    *(bf16x8*)&Ks[0][srow][scol] = kr0;
    *(bf16x8*)&Ks[0][srow][scol + 8] = kr1;
    *(bf16x8*)&Vs[0][srow][scol] = vr0;
    *(bf16x8*)&Vs[0][srow][scol + 8] = vr1;

    int cur = 0;
#pragma unroll 1
    for (int kt = 0; kt < nt; ++kt) {
      __syncthreads();  // buf[cur] staged; buf[cur^1] readers drained
      const int kv0 = kt * KVB;

      // issue next-tile global loads (latency hidden under compute)
      bf16x8 nk0, nk1, nv0, nv1;
      const bool pf = (kt + 1 < nt);
      if (pf) {
        const int nkv = kv0 + KVB;
        nk0 = *(const bf16x8*)&Kh[(size_t)(nkv + srow) * HD + scol];
        nk1 = *(const bf16x8*)&Kh[(size_t)(nkv + srow) * HD + scol + 8];
        nv0 = *(const bf16x8*)&Vh[(size_t)srow * S + nkv + scol];
        nv1 = *(const bf16x8*)&Vh[(size_t)srow * S + nkv + scol + 8];
      }

      // ---- S^T = K Q^T : sc[ni][r] = S[kv0+ni*16+g*4+r][q0w+c16] ----
      f32x4 sc[4] = {};
#pragma unroll
      for (int ks = 0; ks < 2; ++ks) {
#pragma unroll
        for (int ni = 0; ni < 4; ++ni) {
          const bf16x8 kf = *(const bf16x8*)&Ks[cur][ni * 16 + c16][ks * 32 + g * 8];
          sc[ni] = __builtin_amdgcn_mfma_f32_16x16x32_bf16(kf, qf[ks], sc[ni], 0, 0, 0);
        }
      }

      // ---- causal mask (diagonal tile only; wave-uniform branch) ----
      if (kt == qt) {
        const int qq = q0w + c16;
#pragma unroll
        for (int ni = 0; ni < 4; ++ni)
#pragma unroll
          for (int r = 0; r < 4; ++r) {
            const int kv = kv0 + ni * 16 + g * 4 + r;
            if (kv > qq) sc[ni][r] = -1e30f;
          }
      }

      // ---- online softmax: full P row is lane-local ----
      float t = -1e30f;
#pragma unroll
      for (int ni = 0; ni < 4; ++ni)
#pragma unroll
        for (int r = 0; r < 4; ++r) t = fmaxf(t, sc[ni][r]);
      t = fmaxf(t, __shfl_xor(t, 16));
      t = fmaxf(t, __shfl_xor(t, 32));
      const float mnew = fmaxf(m, t);
      const float corr = exp2f(m - mnew);
      m = mnew;
      float rs = 0.f;
#pragma unroll
      for (int ni = 0; ni < 4; ++ni)
#pragma unroll
        for (int r = 0; r < 4; ++r) {
          sc[ni][r] = exp2f(sc[ni][r] - mnew);
          rs += sc[ni][r];
        }
      rs += __shfl_xor(rs, 16);
      rs += __shfl_xor(rs, 32);
      l = l * corr + rs;

      // ---- P -> per-wave LDS, row-major P[q][kv] (no barrier needed) ----
#pragma unroll
      for (int ni = 0; ni < 4; ++ni) {
        bf16x4 hv;
#pragma unroll
        for (int r = 0; r < 4; ++r) hv[r] = (bf16)sc[ni][r];
        *(bf16x4*)&PT[w][c16][ni * 16 + g * 4] = hv;
      }

      // corr for this lane's oacc rows (q = q0w+g*4+r lives at c16 = g*4+r)
      float cb[4];
#pragma unroll
      for (int r = 0; r < 4; ++r)
        cb[r] = __shfl(corr, (lane & 48) + g * 4 + r);
#pragma unroll
      for (int nd = 0; nd < 4; ++nd)
#pragma unroll
        for (int r = 0; r < 4; ++r) oacc[nd][r] *= cb[r];

      // ---- O += P V : A = P[q][kv] from PT, B = V^T[kv][d] from Vs ----
#pragma unroll
      for (int ks = 0; ks < 2; ++ks) {
        const bf16x8 pa = *(const bf16x8*)&PT[w][c16][ks * 32 + g * 8];
#pragma unroll
        for (int nd = 0; nd < 4; ++nd) {
          const bf16x8 bv = *(const bf16x8*)&Vs[cur][nd * 16 + c16][ks * 32 + g * 8];
          oacc[nd] = __builtin_amdgcn_mfma_f32_16x16x32_bf16(pa, bv, oacc[nd], 0, 0, 0);
        }
      }

      // ---- write next tile into other buffer (readers already drained) ----
      if (pf) {
        *(bf16x8*)&Ks[cur ^ 1][srow][scol] = nk0;
        *(bf16x8*)&Ks[cur ^ 1][srow][scol + 8] = nk1;
        *(bf16x8*)&Vs[cur ^ 1][srow][scol] = nv0;
        *(bf16x8*)&Vs[cur ^ 1][srow][scol + 8] = nv1;
      }
      cur ^= 1;
    }

    // ---- epilogue: broadcast l to oacc layout, normalize, write ctx ----
    float lb[4];
#pragma unroll
    for (int r = 0; r < 4; ++r)
      lb[r] = __shfl(l, (lane & 48) + g * 4 + r);
#pragma unroll
    for (int nd = 0; nd < 4; ++nd)
#pragma unroll
      for (int r = 0; r < 4; ++r) {
        const int q = q0w + g * 4 + r;
        const int col = h * 64 + nd * 16 + c16;
        ctx[((size_t)b * S + q) * 1024 + col] = (bf16)(oacc[nd][r] / lb[r]);
      }
  }
}

// ---------------------------------------------------------------------------
extern "C" void kernel_launch(void* const* d_in, const int* in_sizes, int n_in,
                              void* d_out, int out_size, void* d_ws, size_t ws_size,
                              hipStream_t stream) {
  (void)in_sizes; (void)n_in; (void)out_size; (void)ws_size;
  const float* query = (const float*)d_in[0];
  const float* key   = (const float*)d_in[1];
  const float* value = (const float*)d_in[2];
  // d_in[3] = attn_mask (causal triu) — structural, not read
  const float* q_w = (const float*)d_in[4];
  const float* q_b = (const float*)d_in[5];
  const float* k_w = (const float*)d_in[6];
  const float* k_b = (const float*)d_in[7];
  const float* v_w = (const float*)d_in[8];
  const float* v_b = (const float*)d_in[9];
  const float* o_w = (const float*)d_in[10];
  const float* o_b = (const float*)d_in[11];

  const size_t NELEM = (size_t)4096 * 1024;  // B*S*D
  bf16* Qbuf = (bf16*)d_ws;
  bf16* Kbuf = Qbuf + NELEM;
  bf16* Vbuf = Kbuf + NELEM;  // [B,H,hd,S]
  bf16* ctxb = Vbuf + NELEM;

  const dim3 blk(256);
  const dim3 ggrid(8, 32);

  // fold 1/sqrt(64) * log2(e) into Q so attention softmax runs in exp2 domain
  const float QSCALE = 0.125f * 1.44269504088896f;

  gemm_bt_kernel<false, 1><<<ggrid, blk, 0, stream>>>(query, q_w, q_b, Qbuf, QSCALE);
  gemm_bt_kernel<false, 1><<<ggrid, blk, 0, stream>>>(key, k_w, k_b, Kbuf, 1.0f);
  gemm_bt_kernel<false, 2><<<ggrid, blk, 0, stream>>>(value, v_w, v_b, Vbuf, 1.0f);

  attn_kernel<<<dim3(32, 16), blk, 0, stream>>>(Qbuf, Kbuf, Vbuf, ctxb);

  gemm_bt_kernel<true, 0><<<ggrid, blk, 0, stream>>>(ctxb, o_w, o_b, d_out, 1.0f);
}

// Round 4
// 151.850 us; speedup vs baseline: 2.3146x; 1.4016x over previous
//
#include <hip/hip_runtime.h>
#include <hip/hip_bf16.h>

typedef __bf16 bf16;
typedef __attribute__((ext_vector_type(8))) __bf16 bf16x8;
typedef __attribute__((ext_vector_type(4))) __bf16 bf16x4;
typedef __attribute__((ext_vector_type(4))) float f32x4;

// ===========================================================================
// fp32 -> bf16 conversion pass (7 segments in one launch)
// ===========================================================================
struct CvtArgs {
  const float* src[7];
  bf16* dst[7];
  int n4[7];  // element count / 4
};

__global__ __launch_bounds__(256) void cvt_kernel(CvtArgs a) {
  const int seg = blockIdx.y;
  const float4* s = (const float4*)a.src[seg];
  bf16x4* d = (bf16x4*)a.dst[seg];
  const int n = a.n4[seg];
  const int stride = gridDim.x * 256;
  for (int i = blockIdx.x * 256 + threadIdx.x; i < n; i += stride) {
    const float4 v = s[i];
    bf16x4 h;
    h[0] = (bf16)v.x; h[1] = (bf16)v.y; h[2] = (bf16)v.z; h[3] = (bf16)v.w;
    d[i] = h;
  }
}

// ===========================================================================
// bf16 GEMM core: C[M,N] = (A[M,K] @ W[N,K]^T + bias) * scale
// M=4096, N=K=1024. BM=BN=128, BK=64. global_load_lds width-16 staging,
// linear LDS (T2 swizzle null at 2-phase schedule — m252), 2 barriers/K-step.
// mode 0: fp32 [M,N]; mode 1: bf16 [B,H,S,hd] (Q,K); mode 2: bf16 [B,H,hd,S] (V^T)
// ===========================================================================
__device__ __forceinline__ void gload16(const void* g, void* l) {
  __builtin_amdgcn_global_load_lds(
      (const __attribute__((address_space(1))) void*)g,
      (__attribute__((address_space(3))) void*)l, 16, 0, 0);
}

__device__ __forceinline__ void gemm_core(const bf16* __restrict__ A,
                                          const bf16* __restrict__ W,
                                          const float* __restrict__ bias,
                                          void* __restrict__ C,
                                          float scale, int mode) {
  constexpr int K = 1024, N = 1024;
  constexpr int BK = 64;
  __shared__ __align__(16) bf16 As[128 * BK];
  __shared__ __align__(16) bf16 Bs[128 * BK];

  const int tid = threadIdx.x;
  const int lane = tid & 63;
  const int w = tid >> 6;
  const int wr = w >> 1, wc = w & 1;
  const int g = lane >> 4, c16 = lane & 15;
  const int row0 = blockIdx.y * 128;
  const int col0 = blockIdx.x * 128;

  // staging geometry: dest_off bytes = p*4096 + tid*16 ; row stride 128B
  const int srow = tid >> 3;         // + p*32
  const int scol = (tid & 7) * 8;    // elem col within BK
  const int sdst = tid * 8;          // + p*2048 (elems)

  f32x4 acc[4][4] = {};

  for (int kt = 0; kt < K / BK; ++kt) {
    const int k0 = kt * BK;
    __syncthreads();  // prev tile readers done
#pragma unroll
    for (int p = 0; p < 4; ++p) {
      gload16(&A[(size_t)(row0 + p * 32 + srow) * K + k0 + scol], &As[p * 2048 + sdst]);
      gload16(&W[(size_t)(col0 + p * 32 + srow) * K + k0 + scol], &Bs[p * 2048 + sdst]);
    }
    __syncthreads();  // drains vmcnt(0): tile resident

    bf16x8 a[4][2], b[4][2];
#pragma unroll
    for (int m = 0; m < 4; ++m)
#pragma unroll
      for (int ks = 0; ks < 2; ++ks)
        a[m][ks] = *(const bf16x8*)&As[(wr * 64 + m * 16 + c16) * BK + ks * 32 + g * 8];
#pragma unroll
    for (int n = 0; n < 4; ++n)
#pragma unroll
      for (int ks = 0; ks < 2; ++ks)
        b[n][ks] = *(const bf16x8*)&Bs[(wc * 64 + n * 16 + c16) * BK + ks * 32 + g * 8];
#pragma unroll
    for (int ks = 0; ks < 2; ++ks)
#pragma unroll
      for (int m = 0; m < 4; ++m)
#pragma unroll
        for (int n = 0; n < 4; ++n)
          acc[m][n] = __builtin_amdgcn_mfma_f32_16x16x32_bf16(a[m][ks], b[n][ks], acc[m][n], 0, 0, 0);
  }

#pragma unroll
  for (int m = 0; m < 4; ++m) {
#pragma unroll
    for (int n = 0; n < 4; ++n) {
      const int col = col0 + wc * 64 + n * 16 + c16;
      if (mode == 2) {
        const int row = row0 + wr * 64 + m * 16 + g * 4;  // s base, mult of 4
        const int bb = row >> 11, s = row & 2047;
        const int hh = col >> 6, j = col & 63;
        bf16x4 hv;
#pragma unroll
        for (int r = 0; r < 4; ++r)
          hv[r] = (bf16)((acc[m][n][r] + bias[col]) * scale);
        *(bf16x4*)&((bf16*)C)[(((size_t)bb * 16 + hh) * 64 + j) * 2048 + s] = hv;
      } else {
#pragma unroll
        for (int r = 0; r < 4; ++r) {
          const int row = row0 + wr * 64 + m * 16 + g * 4 + r;
          const float v = (acc[m][n][r] + bias[col]) * scale;
          if (mode == 1) {
            const int bb = row >> 11, s = row & 2047;
            const int hh = col >> 6, j = col & 63;
            ((bf16*)C)[(((size_t)bb * 16 + hh) * 2048 + s) * 64 + j] = (bf16)v;
          } else {
            ((float*)C)[(size_t)row * N + col] = v;
          }
        }
      }
    }
  }
}

__global__ __launch_bounds__(256) void qkv_gemm_kernel(
    const bf16* __restrict__ qa, const bf16* __restrict__ ka, const bf16* __restrict__ va,
    const bf16* __restrict__ qw, const bf16* __restrict__ kw, const bf16* __restrict__ vw,
    const float* __restrict__ qb, const float* __restrict__ kb, const float* __restrict__ vb,
    bf16* __restrict__ Qo, bf16* __restrict__ Ko, bf16* __restrict__ Vo, float qscale) {
  const int z = blockIdx.z;
  const bf16* A = (z == 0) ? qa : (z == 1) ? ka : va;
  const bf16* W = (z == 0) ? qw : (z == 1) ? kw : vw;
  const float* bias = (z == 0) ? qb : (z == 1) ? kb : vb;
  bf16* C = (z == 0) ? Qo : (z == 1) ? Ko : Vo;
  const float scale = (z == 0) ? qscale : 1.0f;
  const int mode = (z == 2) ? 2 : 1;
  gemm_core(A, W, bias, C, scale, mode);
}

__global__ __launch_bounds__(256) void o_gemm_kernel(
    const bf16* __restrict__ A, const bf16* __restrict__ W,
    const float* __restrict__ bias, float* __restrict__ C) {
  gemm_core(A, W, bias, C, 1.0f, 0);
}

// ===========================================================================
// Legacy fp32-input GEMM (fallback when ws too small for conversion buffers)
// ===========================================================================
template <bool A_BF16, int OUT_MODE>
__global__ __launch_bounds__(256) void gemm_bt_kernel(
    const void* __restrict__ Aptr, const float* __restrict__ Bt,
    const float* __restrict__ bias, void* __restrict__ Cptr, float scale) {
  constexpr int K = 1024, N = 1024;
  constexpr int BM = 128, BK = 32;
  constexpr int LSTR = BK + 8;
  __shared__ __align__(16) bf16 As[BM][LSTR];
  __shared__ __align__(16) bf16 Bs[BM][LSTR];

  const int tid = threadIdx.x;
  const int lane = tid & 63;
  const int w = tid >> 6;
  const int wr = w >> 1, wc = w & 1;
  const int g = lane >> 4, c16 = lane & 15;
  const int row0 = blockIdx.y * BM;
  const int col0 = blockIdx.x * BM;

  f32x4 acc[4][4] = {};

  for (int kt = 0; kt < K / BK; ++kt) {
    const int k0 = kt * BK;
    if constexpr (!A_BF16) {
      const float* A = (const float*)Aptr;
#pragma unroll
      for (int i = 0; i < 4; ++i) {
        const int r = (tid >> 3) + i * 32;
        const int c = (tid & 7) * 4;
        const float4 v = *(const float4*)(&A[(size_t)(row0 + r) * K + k0 + c]);
        bf16x4 hv;
        hv[0] = (bf16)v.x; hv[1] = (bf16)v.y; hv[2] = (bf16)v.z; hv[3] = (bf16)v.w;
        *(bf16x4*)&As[r][c] = hv;
      }
    } else {
      const bf16* A = (const bf16*)Aptr;
#pragma unroll
      for (int i = 0; i < 2; ++i) {
        const int r = (tid >> 2) + i * 64;
        const int c = (tid & 3) * 8;
        *(bf16x8*)&As[r][c] = *(const bf16x8*)(&A[(size_t)(row0 + r) * K + k0 + c]);
      }
    }
#pragma unroll
    for (int i = 0; i < 4; ++i) {
      const int r = (tid >> 3) + i * 32;
      const int c = (tid & 7) * 4;
      const float4 v = *(const float4*)(&Bt[(size_t)(col0 + r) * K + k0 + c]);
      bf16x4 hv;
      hv[0] = (bf16)v.x; hv[1] = (bf16)v.y; hv[2] = (bf16)v.z; hv[3] = (bf16)v.w;
      *(bf16x4*)&Bs[r][c] = hv;
    }
    __syncthreads();

    bf16x8 a[4], b[4];
#pragma unroll
    for (int m = 0; m < 4; ++m)
      a[m] = *(bf16x8*)&As[wr * 64 + m * 16 + c16][g * 8];
#pragma unroll
    for (int n = 0; n < 4; ++n)
      b[n] = *(bf16x8*)&Bs[wc * 64 + n * 16 + c16][g * 8];
#pragma unroll
    for (int m = 0; m < 4; ++m)
#pragma unroll
      for (int n = 0; n < 4; ++n)
        acc[m][n] = __builtin_amdgcn_mfma_f32_16x16x32_bf16(a[m], b[n], acc[m][n], 0, 0, 0);
    __syncthreads();
  }

#pragma unroll
  for (int m = 0; m < 4; ++m) {
#pragma unroll
    for (int n = 0; n < 4; ++n) {
      const int col = col0 + wc * 64 + n * 16 + c16;
      if constexpr (OUT_MODE == 2) {
        const int row = row0 + wr * 64 + m * 16 + g * 4;
        const int bb = row >> 11, s = row & 2047;
        const int hh = col >> 6, j = col & 63;
        bf16x4 hv;
#pragma unroll
        for (int r = 0; r < 4; ++r)
          hv[r] = (bf16)((acc[m][n][r] + bias[col]) * scale);
        *(bf16x4*)&((bf16*)Cptr)[(((size_t)bb * 16 + hh) * 64 + j) * 2048 + s] = hv;
      } else {
#pragma unroll
        for (int r = 0; r < 4; ++r) {
          const int row = row0 + wr * 64 + m * 16 + g * 4 + r;
          const float v = (acc[m][n][r] + bias[col]) * scale;
          if constexpr (OUT_MODE == 1) {
            const int bb = row >> 11, s = row & 2047;
            const int hh = col >> 6, j = col & 63;
            ((bf16*)Cptr)[(((size_t)bb * 16 + hh) * 2048 + s) * 64 + j] = (bf16)v;
          } else {
            ((float*)Cptr)[(size_t)row * N + col] = v;
          }
        }
      }
    }
  }
}

// ===========================================================================
// Causal flash attention, swapped-QK^T form (unchanged from round 3).
// Q,K bf16 [B=2,H=16,S=2048,hd=64]; V bf16 [B,H,hd=64,S=2048] (pre-transposed).
// Q pre-scaled by 0.125*log2(e) -> exp2 softmax. 4 waves, 16 q-rows/wave.
// Causal pairing j & 31-j -> 33 KV tiles per block. Double-buffered staging.
// ===========================================================================
__global__ __launch_bounds__(256) void attn_kernel(
    const bf16* __restrict__ Q, const bf16* __restrict__ Kb,
    const bf16* __restrict__ Vt, bf16* __restrict__ ctx) {
  constexpr int S = 2048, HD = 64, KVB = 64;
  constexpr int PS = 72;
  __shared__ __align__(16) bf16 Ks[2][KVB][PS];
  __shared__ __align__(16) bf16 Vs[2][HD][PS];
  __shared__ __align__(16) bf16 PT[4][16][PS];

  const int tid = threadIdx.x;
  const int lane = tid & 63;
  const int w = tid >> 6;
  const int g = lane >> 4, c16 = lane & 15;
  const int bh = blockIdx.x;
  const int pj = blockIdx.y;
  const int b = bh >> 4, h = bh & 15;

  const bf16* Qh = Q + (size_t)bh * S * HD;
  const bf16* Kh = Kb + (size_t)bh * S * HD;
  const bf16* Vh = Vt + (size_t)bh * HD * S;

  const int srow = tid >> 2;
  const int scol = (tid & 3) * 16;

#pragma unroll 1
  for (int phase = 0; phase < 2; ++phase) {
    const int qt = (phase == 0) ? pj : 31 - pj;
    const int q0w = qt * 64 + w * 16;
    const int nt = qt + 1;

    bf16x8 qf[2];
#pragma unroll
    for (int ks = 0; ks < 2; ++ks)
      qf[ks] = *(const bf16x8*)&Qh[(size_t)(q0w + c16) * HD + ks * 32 + g * 8];

    f32x4 oacc[4] = {};
    float m = -1e30f, l = 0.f;

    bf16x8 kr0 = *(const bf16x8*)&Kh[(size_t)srow * HD + scol];
    bf16x8 kr1 = *(const bf16x8*)&Kh[(size_t)srow * HD + scol + 8];
    bf16x8 vr0 = *(const bf16x8*)&Vh[(size_t)srow * S + scol];
    bf16x8 vr1 = *(const bf16x8*)&Vh[(size_t)srow * S + scol + 8];
    __syncthreads();
    *(bf16x8*)&Ks[0][srow][scol] = kr0;
    *(bf16x8*)&Ks[0][srow][scol + 8] = kr1;
    *(bf16x8*)&Vs[0][srow][scol] = vr0;
    *(bf16x8*)&Vs[0][srow][scol + 8] = vr1;

    int cur = 0;
#pragma unroll 1
    for (int kt = 0; kt < nt; ++kt) {
      __syncthreads();
      const int kv0 = kt * KVB;

      bf16x8 nk0, nk1, nv0, nv1;
      const bool pf = (kt + 1 < nt);
      if (pf) {
        const int nkv = kv0 + KVB;
        nk0 = *(const bf16x8*)&Kh[(size_t)(nkv + srow) * HD + scol];
        nk1 = *(const bf16x8*)&Kh[(size_t)(nkv + srow) * HD + scol + 8];
        nv0 = *(const bf16x8*)&Vh[(size_t)srow * S + nkv + scol];
        nv1 = *(const bf16x8*)&Vh[(size_t)srow * S + nkv + scol + 8];
      }

      f32x4 sc[4] = {};
#pragma unroll
      for (int ks = 0; ks < 2; ++ks) {
#pragma unroll
        for (int ni = 0; ni < 4; ++ni) {
          const bf16x8 kf = *(const bf16x8*)&Ks[cur][ni * 16 + c16][ks * 32 + g * 8];
          sc[ni] = __builtin_amdgcn_mfma_f32_16x16x32_bf16(kf, qf[ks], sc[ni], 0, 0, 0);
        }
      }

      if (kt == qt) {
        const int qq = q0w + c16;
#pragma unroll
        for (int ni = 0; ni < 4; ++ni)
#pragma unroll
          for (int r = 0; r < 4; ++r) {
            const int kv = kv0 + ni * 16 + g * 4 + r;
            if (kv > qq) sc[ni][r] = -1e30f;
          }
      }

      float t = -1e30f;
#pragma unroll
      for (int ni = 0; ni < 4; ++ni)
#pragma unroll
        for (int r = 0; r < 4; ++r) t = fmaxf(t, sc[ni][r]);
      t = fmaxf(t, __shfl_xor(t, 16));
      t = fmaxf(t, __shfl_xor(t, 32));
      const float mnew = fmaxf(m, t);
      const float corr = exp2f(m - mnew);
      m = mnew;
      float rs = 0.f;
#pragma unroll
      for (int ni = 0; ni < 4; ++ni)
#pragma unroll
        for (int r = 0; r < 4; ++r) {
          sc[ni][r] = exp2f(sc[ni][r] - mnew);
          rs += sc[ni][r];
        }
      rs += __shfl_xor(rs, 16);
      rs += __shfl_xor(rs, 32);
      l = l * corr + rs;

#pragma unroll
      for (int ni = 0; ni < 4; ++ni) {
        bf16x4 hv;
#pragma unroll
        for (int r = 0; r < 4; ++r) hv[r] = (bf16)sc[ni][r];
        *(bf16x4*)&PT[w][c16][ni * 16 + g * 4] = hv;
      }

      float cb[4];
#pragma unroll
      for (int r = 0; r < 4; ++r)
        cb[r] = __shfl(corr, (lane & 48) + g * 4 + r);
#pragma unroll
      for (int nd = 0; nd < 4; ++nd)
#pragma unroll
        for (int r = 0; r < 4; ++r) oacc[nd][r] *= cb[r];

#pragma unroll
      for (int ks = 0; ks < 2; ++ks) {
        const bf16x8 pa = *(const bf16x8*)&PT[w][c16][ks * 32 + g * 8];
#pragma unroll
        for (int nd = 0; nd < 4; ++nd) {
          const bf16x8 bv = *(const bf16x8*)&Vs[cur][nd * 16 + c16][ks * 32 + g * 8];
          oacc[nd] = __builtin_amdgcn_mfma_f32_16x16x32_bf16(pa, bv, oacc[nd], 0, 0, 0);
        }
      }

      if (pf) {
        *(bf16x8*)&Ks[cur ^ 1][srow][scol] = nk0;
        *(bf16x8*)&Ks[cur ^ 1][srow][scol + 8] = nk1;
        *(bf16x8*)&Vs[cur ^ 1][srow][scol] = nv0;
        *(bf16x8*)&Vs[cur ^ 1][srow][scol + 8] = nv1;
      }
      cur ^= 1;
    }

    float lb[4];
#pragma unroll
    for (int r = 0; r < 4; ++r)
      lb[r] = __shfl(l, (lane & 48) + g * 4 + r);
#pragma unroll
    for (int nd = 0; nd < 4; ++nd)
#pragma unroll
      for (int r = 0; r < 4; ++r) {
        const int q = q0w + g * 4 + r;
        const int col = h * 64 + nd * 16 + c16;
        ctx[((size_t)b * S + q) * 1024 + col] = (bf16)(oacc[nd][r] / lb[r]);
      }
  }
}

// ===========================================================================
extern "C" void kernel_launch(void* const* d_in, const int* in_sizes, int n_in,
                              void* d_out, int out_size, void* d_ws, size_t ws_size,
                              hipStream_t stream) {
  (void)in_sizes; (void)n_in; (void)out_size;
  const float* query = (const float*)d_in[0];
  const float* key   = (const float*)d_in[1];
  const float* value = (const float*)d_in[2];
  // d_in[3] = attn_mask (causal triu) — structural, not read
  const float* q_w = (const float*)d_in[4];
  const float* q_b = (const float*)d_in[5];
  const float* k_w = (const float*)d_in[6];
  const float* k_b = (const float*)d_in[7];
  const float* v_w = (const float*)d_in[8];
  const float* v_b = (const float*)d_in[9];
  const float* o_w = (const float*)d_in[10];
  const float* o_b = (const float*)d_in[11];

  const size_t NELEM = (size_t)4096 * 1024;  // B*S*D
  const size_t WELEM = (size_t)1024 * 1024;
  bf16* Qbuf = (bf16*)d_ws;        //  0 MB
  bf16* Kbuf = Qbuf + NELEM;       //  8 MB
  bf16* Vbuf = Kbuf + NELEM;       // 16 MB  [B,H,hd,S]
  bf16* ctxb = Vbuf + NELEM;       // 24 MB

  const dim3 blk(256);
  const float QSCALE = 0.125f * 1.44269504088896f;  // 1/sqrt(64) * log2(e)

  const size_t need = 64ull * 1024 * 1024;
  if (ws_size >= need) {
    // ---- fast path: pre-convert everything to bf16, global_load_lds GEMMs
    bf16* qbf  = ctxb + NELEM;       // 32 MB
    bf16* kbf  = qbf + NELEM;        // 40 MB
    bf16* vbf  = kbf + NELEM;        // 48 MB
    bf16* qwbf = vbf + NELEM;        // 56 MB
    bf16* kwbf = qwbf + WELEM;       // 58 MB
    bf16* vwbf = kwbf + WELEM;       // 60 MB
    bf16* owbf = vwbf + WELEM;       // 62 MB .. 64 MB

    CvtArgs ca;
    ca.src[0] = query; ca.dst[0] = qbf;  ca.n4[0] = (int)(NELEM / 4);
    ca.src[1] = key;   ca.dst[1] = kbf;  ca.n4[1] = (int)(NELEM / 4);
    ca.src[2] = value; ca.dst[2] = vbf;  ca.n4[2] = (int)(NELEM / 4);
    ca.src[3] = q_w;   ca.dst[3] = qwbf; ca.n4[3] = (int)(WELEM / 4);
    ca.src[4] = k_w;   ca.dst[4] = kwbf; ca.n4[4] = (int)(WELEM / 4);
    ca.src[5] = v_w;   ca.dst[5] = vwbf; ca.n4[5] = (int)(WELEM / 4);
    ca.src[6] = o_w;   ca.dst[6] = owbf; ca.n4[6] = (int)(WELEM / 4);
    cvt_kernel<<<dim3(256, 7), blk, 0, stream>>>(ca);

    qkv_gemm_kernel<<<dim3(8, 32, 3), blk, 0, stream>>>(
        qbf, kbf, vbf, qwbf, kwbf, vwbf, q_b, k_b, v_b, Qbuf, Kbuf, Vbuf, QSCALE);

    attn_kernel<<<dim3(32, 16), blk, 0, stream>>>(Qbuf, Kbuf, Vbuf, ctxb);

    o_gemm_kernel<<<dim3(8, 32), blk, 0, stream>>>(ctxb, owbf, o_b, (float*)d_out);
  } else {
    // ---- fallback: round-3 path (fp32-input reg-staged GEMMs)
    const dim3 ggrid(8, 32);
    gemm_bt_kernel<false, 1><<<ggrid, blk, 0, stream>>>(query, q_w, q_b, Qbuf, QSCALE);
    gemm_bt_kernel<false, 1><<<ggrid, blk, 0, stream>>>(key, k_w, k_b, Kbuf, 1.0f);
    gemm_bt_kernel<false, 2><<<ggrid, blk, 0, stream>>>(value, v_w, v_b, Vbuf, 1.0f);
    attn_kernel<<<dim3(32, 16), blk, 0, stream>>>(Qbuf, Kbuf, Vbuf, ctxb);
    gemm_bt_kernel<true, 0><<<ggrid, blk, 0, stream>>>(ctxb, o_w, o_b, d_out, 1.0f);
  }
}

// Round 5
// 144.882 us; speedup vs baseline: 2.4259x; 1.0481x over previous
//
#include <hip/hip_runtime.h>
#include <hip/hip_bf16.h>

typedef __bf16 bf16;
typedef __attribute__((ext_vector_type(8))) __bf16 bf16x8;
typedef __attribute__((ext_vector_type(4))) __bf16 bf16x4;
typedef __attribute__((ext_vector_type(4))) float f32x4;

// ===========================================================================
// fp32 -> bf16 conversion pass (7 segments in one launch)
// ===========================================================================
struct CvtArgs {
  const float* src[7];
  bf16* dst[7];
  int n4[7];  // element count / 4
};

__global__ __launch_bounds__(256) void cvt_kernel(CvtArgs a) {
  const int seg = blockIdx.y;
  const float4* s = (const float4*)a.src[seg];
  bf16x4* d = (bf16x4*)a.dst[seg];
  const int n = a.n4[seg];
  const int stride = gridDim.x * 256;
  for (int i = blockIdx.x * 256 + threadIdx.x; i < n; i += stride) {
    const float4 v = s[i];
    bf16x4 h;
    h[0] = (bf16)v.x; h[1] = (bf16)v.y; h[2] = (bf16)v.z; h[3] = (bf16)v.w;
    d[i] = h;
  }
}

// ===========================================================================
// bf16 GEMM core: C[M,N] = (A[M,K] @ W[N,K]^T + bias) * scale
// M=4096, N=K=1024. BM=BN=128, BK=64. global_load_lds width-16 staging,
// linear LDS, 2 barriers/K-step.
// mode 0: fp32 [M,N]; mode 1: bf16 [B,H,S,hd] (Q,K); mode 2: bf16 [B,H,hd,S] (V^T)
// ===========================================================================
__device__ __forceinline__ void gload16(const void* g, void* l) {
  __builtin_amdgcn_global_load_lds(
      (const __attribute__((address_space(1))) void*)g,
      (__attribute__((address_space(3))) void*)l, 16, 0, 0);
}

__device__ __forceinline__ void gemm_core(const bf16* __restrict__ A,
                                          const bf16* __restrict__ W,
                                          const float* __restrict__ bias,
                                          void* __restrict__ C,
                                          float scale, int mode) {
  constexpr int K = 1024, N = 1024;
  constexpr int BK = 64;
  __shared__ __align__(16) bf16 As[128 * BK];
  __shared__ __align__(16) bf16 Bs[128 * BK];

  const int tid = threadIdx.x;
  const int lane = tid & 63;
  const int w = tid >> 6;
  const int wr = w >> 1, wc = w & 1;
  const int g = lane >> 4, c16 = lane & 15;
  const int row0 = blockIdx.y * 128;
  const int col0 = blockIdx.x * 128;

  const int srow = tid >> 3;
  const int scol = (tid & 7) * 8;
  const int sdst = tid * 8;

  f32x4 acc[4][4] = {};

  for (int kt = 0; kt < K / BK; ++kt) {
    const int k0 = kt * BK;
    __syncthreads();
#pragma unroll
    for (int p = 0; p < 4; ++p) {
      gload16(&A[(size_t)(row0 + p * 32 + srow) * K + k0 + scol], &As[p * 2048 + sdst]);
      gload16(&W[(size_t)(col0 + p * 32 + srow) * K + k0 + scol], &Bs[p * 2048 + sdst]);
    }
    __syncthreads();

    bf16x8 a[4][2], b[4][2];
#pragma unroll
    for (int m = 0; m < 4; ++m)
#pragma unroll
      for (int ks = 0; ks < 2; ++ks)
        a[m][ks] = *(const bf16x8*)&As[(wr * 64 + m * 16 + c16) * BK + ks * 32 + g * 8];
#pragma unroll
    for (int n = 0; n < 4; ++n)
#pragma unroll
      for (int ks = 0; ks < 2; ++ks)
        b[n][ks] = *(const bf16x8*)&Bs[(wc * 64 + n * 16 + c16) * BK + ks * 32 + g * 8];
#pragma unroll
    for (int ks = 0; ks < 2; ++ks)
#pragma unroll
      for (int m = 0; m < 4; ++m)
#pragma unroll
        for (int n = 0; n < 4; ++n)
          acc[m][n] = __builtin_amdgcn_mfma_f32_16x16x32_bf16(a[m][ks], b[n][ks], acc[m][n], 0, 0, 0);
  }

#pragma unroll
  for (int m = 0; m < 4; ++m) {
#pragma unroll
    for (int n = 0; n < 4; ++n) {
      const int col = col0 + wc * 64 + n * 16 + c16;
      if (mode == 2) {
        const int row = row0 + wr * 64 + m * 16 + g * 4;
        const int bb = row >> 11, s = row & 2047;
        const int hh = col >> 6, j = col & 63;
        bf16x4 hv;
#pragma unroll
        for (int r = 0; r < 4; ++r)
          hv[r] = (bf16)((acc[m][n][r] + bias[col]) * scale);
        *(bf16x4*)&((bf16*)C)[(((size_t)bb * 16 + hh) * 64 + j) * 2048 + s] = hv;
      } else {
#pragma unroll
        for (int r = 0; r < 4; ++r) {
          const int row = row0 + wr * 64 + m * 16 + g * 4 + r;
          const float v = (acc[m][n][r] + bias[col]) * scale;
          if (mode == 1) {
            const int bb = row >> 11, s = row & 2047;
            const int hh = col >> 6, j = col & 63;
            ((bf16*)C)[(((size_t)bb * 16 + hh) * 2048 + s) * 64 + j] = (bf16)v;
          } else {
            ((float*)C)[(size_t)row * N + col] = v;
          }
        }
      }
    }
  }
}

__global__ __launch_bounds__(256) void qkv_gemm_kernel(
    const bf16* __restrict__ qa, const bf16* __restrict__ ka, const bf16* __restrict__ va,
    const bf16* __restrict__ qw, const bf16* __restrict__ kw, const bf16* __restrict__ vw,
    const float* __restrict__ qb, const float* __restrict__ kb, const float* __restrict__ vb,
    bf16* __restrict__ Qo, bf16* __restrict__ Ko, bf16* __restrict__ Vo, float qscale) {
  const int z = blockIdx.z;
  const bf16* A = (z == 0) ? qa : (z == 1) ? ka : va;
  const bf16* W = (z == 0) ? qw : (z == 1) ? kw : vw;
  const float* bias = (z == 0) ? qb : (z == 1) ? kb : vb;
  bf16* C = (z == 0) ? Qo : (z == 1) ? Ko : Vo;
  const float scale = (z == 0) ? qscale : 1.0f;
  const int mode = (z == 2) ? 2 : 1;
  gemm_core(A, W, bias, C, scale, mode);
}

__global__ __launch_bounds__(256) void o_gemm_kernel(
    const bf16* __restrict__ A, const bf16* __restrict__ W,
    const float* __restrict__ bias, float* __restrict__ C) {
  gemm_core(A, W, bias, C, 1.0f, 0);
}

// ===========================================================================
// Legacy fp32-input GEMM (fallback when ws too small for conversion buffers)
// ===========================================================================
template <bool A_BF16, int OUT_MODE>
__global__ __launch_bounds__(256) void gemm_bt_kernel(
    const void* __restrict__ Aptr, const float* __restrict__ Bt,
    const float* __restrict__ bias, void* __restrict__ Cptr, float scale) {
  constexpr int K = 1024, N = 1024;
  constexpr int BM = 128, BK = 32;
  constexpr int LSTR = BK + 8;
  __shared__ __align__(16) bf16 As[BM][LSTR];
  __shared__ __align__(16) bf16 Bs[BM][LSTR];

  const int tid = threadIdx.x;
  const int lane = tid & 63;
  const int w = tid >> 6;
  const int wr = w >> 1, wc = w & 1;
  const int g = lane >> 4, c16 = lane & 15;
  const int row0 = blockIdx.y * BM;
  const int col0 = blockIdx.x * BM;

  f32x4 acc[4][4] = {};

  for (int kt = 0; kt < K / BK; ++kt) {
    const int k0 = kt * BK;
    if constexpr (!A_BF16) {
      const float* A = (const float*)Aptr;
#pragma unroll
      for (int i = 0; i < 4; ++i) {
        const int r = (tid >> 3) + i * 32;
        const int c = (tid & 7) * 4;
        const float4 v = *(const float4*)(&A[(size_t)(row0 + r) * K + k0 + c]);
        bf16x4 hv;
        hv[0] = (bf16)v.x; hv[1] = (bf16)v.y; hv[2] = (bf16)v.z; hv[3] = (bf16)v.w;
        *(bf16x4*)&As[r][c] = hv;
      }
    } else {
      const bf16* A = (const bf16*)Aptr;
#pragma unroll
      for (int i = 0; i < 2; ++i) {
        const int r = (tid >> 2) + i * 64;
        const int c = (tid & 3) * 8;
        *(bf16x8*)&As[r][c] = *(const bf16x8*)(&A[(size_t)(row0 + r) * K + k0 + c]);
      }
    }
#pragma unroll
    for (int i = 0; i < 4; ++i) {
      const int r = (tid >> 3) + i * 32;
      const int c = (tid & 7) * 4;
      const float4 v = *(const float4*)(&Bt[(size_t)(col0 + r) * K + k0 + c]);
      bf16x4 hv;
      hv[0] = (bf16)v.x; hv[1] = (bf16)v.y; hv[2] = (bf16)v.z; hv[3] = (bf16)v.w;
      *(bf16x4*)&Bs[r][c] = hv;
    }
    __syncthreads();

    bf16x8 a[4], b[4];
#pragma unroll
    for (int m = 0; m < 4; ++m)
      a[m] = *(bf16x8*)&As[wr * 64 + m * 16 + c16][g * 8];
#pragma unroll
    for (int n = 0; n < 4; ++n)
      b[n] = *(bf16x8*)&Bs[wc * 64 + n * 16 + c16][g * 8];
#pragma unroll
    for (int m = 0; m < 4; ++m)
#pragma unroll
      for (int n = 0; n < 4; ++n)
        acc[m][n] = __builtin_amdgcn_mfma_f32_16x16x32_bf16(a[m], b[n], acc[m][n], 0, 0, 0);
    __syncthreads();
  }

#pragma unroll
  for (int m = 0; m < 4; ++m) {
#pragma unroll
    for (int n = 0; n < 4; ++n) {
      const int col = col0 + wc * 64 + n * 16 + c16;
      if constexpr (OUT_MODE == 2) {
        const int row = row0 + wr * 64 + m * 16 + g * 4;
        const int bb = row >> 11, s = row & 2047;
        const int hh = col >> 6, j = col & 63;
        bf16x4 hv;
#pragma unroll
        for (int r = 0; r < 4; ++r)
          hv[r] = (bf16)((acc[m][n][r] + bias[col]) * scale);
        *(bf16x4*)&((bf16*)Cptr)[(((size_t)bb * 16 + hh) * 64 + j) * 2048 + s] = hv;
      } else {
#pragma unroll
        for (int r = 0; r < 4; ++r) {
          const int row = row0 + wr * 64 + m * 16 + g * 4 + r;
          const float v = (acc[m][n][r] + bias[col]) * scale;
          if constexpr (OUT_MODE == 1) {
            const int bb = row >> 11, s = row & 2047;
            const int hh = col >> 6, j = col & 63;
            ((bf16*)Cptr)[(((size_t)bb * 16 + hh) * 2048 + s) * 64 + j] = (bf16)v;
          } else {
            ((float*)Cptr)[(size_t)row * N + col] = v;
          }
        }
      }
    }
  }
}

// ===========================================================================
// Causal flash attention, swapped-QK^T form.
// Q,K bf16 [B=2,H=16,S=2048,hd=64]; V bf16 [B,H,hd=64,S=2048] (pre-transposed).
// Q pre-scaled by 0.125*log2(e) -> exp2 softmax. 4 waves, 16 q-rows/wave.
// One q-tile (64 rows) per block; grid (32 bh, 32 qt-permuted) = 1024 blocks,
// all co-resident (4/CU, 16 waves/CU). Single-buffered K/V (27.6 KiB LDS),
// 2 barriers/tile, register prefetch of tile t+1 under compute of tile t.
// T13 defer-max (thr=8, log2 domain). T5 setprio around MFMA clusters.
// ===========================================================================
__global__ __launch_bounds__(256) void attn_kernel(
    const bf16* __restrict__ Q, const bf16* __restrict__ Kb,
    const bf16* __restrict__ Vt, bf16* __restrict__ ctx) {
  constexpr int S = 2048, HD = 64, KVB = 64;
  constexpr int PS = 72;
  __shared__ __align__(16) bf16 Ks[KVB][PS];
  __shared__ __align__(16) bf16 Vs[HD][PS];
  __shared__ __align__(16) bf16 PT[4][16][PS];

  const int tid = threadIdx.x;
  const int lane = tid & 63;
  const int w = tid >> 6;
  const int g = lane >> 4, c16 = lane & 15;
  const int bh = blockIdx.x;
  const int b = bh >> 4, h = bh & 15;

  // qt permutation: CU c's four stride-256 blocks sum to ~66 KV-tiles
  const int jj = blockIdx.y;
  const int sub = jj & 7, grp = jj >> 3;
  const int qt = (grp == 0) ? sub : (grp == 1) ? 31 - sub : (grp == 2) ? 8 + sub : 23 - sub;

  const bf16* Qh = Q + (size_t)bh * S * HD;
  const bf16* Kh = Kb + (size_t)bh * S * HD;
  const bf16* Vh = Vt + (size_t)bh * HD * S;

  const int srow = tid >> 2;
  const int scol = (tid & 3) * 16;

  const int q0w = qt * 64 + w * 16;
  const int nt = qt + 1;

  // Q as B-fragment: lane holds Q[q0w+c16][ks*32+g*8 ..+7]
  bf16x8 qf[2];
#pragma unroll
  for (int ks = 0; ks < 2; ++ks)
    qf[ks] = *(const bf16x8*)&Qh[(size_t)(q0w + c16) * HD + ks * 32 + g * 8];

  f32x4 oacc[4] = {};
  float m = -1e30f, l = 0.f;

  // prologue: load tile 0 into regs
  bf16x8 kr0 = *(const bf16x8*)&Kh[(size_t)srow * HD + scol];
  bf16x8 kr1 = *(const bf16x8*)&Kh[(size_t)srow * HD + scol + 8];
  bf16x8 vr0 = *(const bf16x8*)&Vh[(size_t)srow * S + scol];
  bf16x8 vr1 = *(const bf16x8*)&Vh[(size_t)srow * S + scol + 8];

#pragma unroll 1
  for (int kt = 0; kt < nt; ++kt) {
    __syncthreads();  // all waves done reading previous tile
    *(bf16x8*)&Ks[srow][scol] = kr0;
    *(bf16x8*)&Ks[srow][scol + 8] = kr1;
    *(bf16x8*)&Vs[srow][scol] = vr0;
    *(bf16x8*)&Vs[srow][scol + 8] = vr1;
    __syncthreads();  // tile kt resident

    const int kv0 = kt * KVB;
    const bool pf = (kt + 1 < nt);
    if (pf) {
      const int nkv = kv0 + KVB;
      kr0 = *(const bf16x8*)&Kh[(size_t)(nkv + srow) * HD + scol];
      kr1 = *(const bf16x8*)&Kh[(size_t)(nkv + srow) * HD + scol + 8];
      vr0 = *(const bf16x8*)&Vh[(size_t)srow * S + nkv + scol];
      vr1 = *(const bf16x8*)&Vh[(size_t)srow * S + nkv + scol + 8];
    }

    // ---- S^T = K Q^T : sc[ni][r] = S[kv0+ni*16+g*4+r][q0w+c16] ----
    f32x4 sc[4] = {};
    __builtin_amdgcn_s_setprio(1);
#pragma unroll
    for (int ks = 0; ks < 2; ++ks) {
#pragma unroll
      for (int ni = 0; ni < 4; ++ni) {
        const bf16x8 kf = *(const bf16x8*)&Ks[ni * 16 + c16][ks * 32 + g * 8];
        sc[ni] = __builtin_amdgcn_mfma_f32_16x16x32_bf16(kf, qf[ks], sc[ni], 0, 0, 0);
      }
    }
    __builtin_amdgcn_s_setprio(0);

    // ---- causal mask (diagonal tile only; wave-uniform branch) ----
    if (kt == qt) {
      const int qq = q0w + c16;
#pragma unroll
      for (int ni = 0; ni < 4; ++ni)
#pragma unroll
        for (int r = 0; r < 4; ++r) {
          const int kv = kv0 + ni * 16 + g * 4 + r;
          if (kv > qq) sc[ni][r] = -1e30f;
        }
    }

    // ---- online softmax with defer-max (T13, thr=8 in log2 domain) ----
    float t = -1e30f;
#pragma unroll
    for (int ni = 0; ni < 4; ++ni)
#pragma unroll
      for (int r = 0; r < 4; ++r) t = fmaxf(t, sc[ni][r]);
    t = fmaxf(t, __shfl_xor(t, 16));
    t = fmaxf(t, __shfl_xor(t, 32));
    if (!__all(t <= m + 8.0f)) {
      const float mnew = fmaxf(m, t);
      const float corr = exp2f(m - mnew);
      m = mnew;
      l *= corr;
      float cb[4];
#pragma unroll
      for (int r = 0; r < 4; ++r)
        cb[r] = __shfl(corr, (lane & 48) + g * 4 + r);
#pragma unroll
      for (int nd = 0; nd < 4; ++nd)
#pragma unroll
        for (int r = 0; r < 4; ++r) oacc[nd][r] *= cb[r];
    }
    float rs = 0.f;
#pragma unroll
    for (int ni = 0; ni < 4; ++ni)
#pragma unroll
      for (int r = 0; r < 4; ++r) {
        sc[ni][r] = exp2f(sc[ni][r] - m);
        rs += sc[ni][r];
      }
    rs += __shfl_xor(rs, 16);
    rs += __shfl_xor(rs, 32);
    l += rs;

    // ---- P -> per-wave LDS, row-major P[q][kv] (no barrier needed) ----
#pragma unroll
    for (int ni = 0; ni < 4; ++ni) {
      bf16x4 hv;
#pragma unroll
      for (int r = 0; r < 4; ++r) hv[r] = (bf16)sc[ni][r];
      *(bf16x4*)&PT[w][c16][ni * 16 + g * 4] = hv;
    }

    // ---- O += P V : A = P[q][kv] from PT, B = V^T[kv][d] from Vs ----
    __builtin_amdgcn_s_setprio(1);
#pragma unroll
    for (int ks = 0; ks < 2; ++ks) {
      const bf16x8 pa = *(const bf16x8*)&PT[w][c16][ks * 32 + g * 8];
#pragma unroll
      for (int nd = 0; nd < 4; ++nd) {
        const bf16x8 bv = *(const bf16x8*)&Vs[nd * 16 + c16][ks * 32 + g * 8];
        oacc[nd] = __builtin_amdgcn_mfma_f32_16x16x32_bf16(pa, bv, oacc[nd], 0, 0, 0);
      }
    }
    __builtin_amdgcn_s_setprio(0);
  }

  // ---- epilogue: broadcast l to oacc layout, normalize, write ctx ----
  float lb[4];
#pragma unroll
  for (int r = 0; r < 4; ++r)
    lb[r] = __shfl(l, (lane & 48) + g * 4 + r);
#pragma unroll
  for (int nd = 0; nd < 4; ++nd)
#pragma unroll
    for (int r = 0; r < 4; ++r) {
      const int q = q0w + g * 4 + r;
      const int col = h * 64 + nd * 16 + c16;
      ctx[((size_t)b * S + q) * 1024 + col] = (bf16)(oacc[nd][r] / lb[r]);
    }
}

// ===========================================================================
extern "C" void kernel_launch(void* const* d_in, const int* in_sizes, int n_in,
                              void* d_out, int out_size, void* d_ws, size_t ws_size,
                              hipStream_t stream) {
  (void)in_sizes; (void)n_in; (void)out_size;
  const float* query = (const float*)d_in[0];
  const float* key   = (const float*)d_in[1];
  const float* value = (const float*)d_in[2];
  // d_in[3] = attn_mask (causal triu) — structural, not read
  const float* q_w = (const float*)d_in[4];
  const float* q_b = (const float*)d_in[5];
  const float* k_w = (const float*)d_in[6];
  const float* k_b = (const float*)d_in[7];
  const float* v_w = (const float*)d_in[8];
  const float* v_b = (const float*)d_in[9];
  const float* o_w = (const float*)d_in[10];
  const float* o_b = (const float*)d_in[11];

  const size_t NELEM = (size_t)4096 * 1024;  // B*S*D
  const size_t WELEM = (size_t)1024 * 1024;
  bf16* Qbuf = (bf16*)d_ws;        //  0 MB
  bf16* Kbuf = Qbuf + NELEM;       //  8 MB
  bf16* Vbuf = Kbuf + NELEM;       // 16 MB  [B,H,hd,S]
  bf16* ctxb = Vbuf + NELEM;       // 24 MB

  const dim3 blk(256);
  const float QSCALE = 0.125f * 1.44269504088896f;  // 1/sqrt(64) * log2(e)

  const size_t need = 64ull * 1024 * 1024;
  if (ws_size >= need) {
    // ---- fast path: pre-convert everything to bf16, global_load_lds GEMMs
    bf16* qbf  = ctxb + NELEM;       // 32 MB
    bf16* kbf  = qbf + NELEM;        // 40 MB
    bf16* vbf  = kbf + NELEM;        // 48 MB
    bf16* qwbf = vbf + NELEM;        // 56 MB
    bf16* kwbf = qwbf + WELEM;       // 58 MB
    bf16* vwbf = kwbf + WELEM;       // 60 MB
    bf16* owbf = vwbf + WELEM;       // 62 MB .. 64 MB

    CvtArgs ca;
    ca.src[0] = query; ca.dst[0] = qbf;  ca.n4[0] = (int)(NELEM / 4);
    ca.src[1] = key;   ca.dst[1] = kbf;  ca.n4[1] = (int)(NELEM / 4);
    ca.src[2] = value; ca.dst[2] = vbf;  ca.n4[2] = (int)(NELEM / 4);
    ca.src[3] = q_w;   ca.dst[3] = qwbf; ca.n4[3] = (int)(WELEM / 4);
    ca.src[4] = k_w;   ca.dst[4] = kwbf; ca.n4[4] = (int)(WELEM / 4);
    ca.src[5] = v_w;   ca.dst[5] = vwbf; ca.n4[5] = (int)(WELEM / 4);
    ca.src[6] = o_w;   ca.dst[6] = owbf; ca.n4[6] = (int)(WELEM / 4);
    cvt_kernel<<<dim3(256, 7), blk, 0, stream>>>(ca);

    qkv_gemm_kernel<<<dim3(8, 32, 3), blk, 0, stream>>>(
        qbf, kbf, vbf, qwbf, kwbf, vwbf, q_b, k_b, v_b, Qbuf, Kbuf, Vbuf, QSCALE);

    attn_kernel<<<dim3(32, 32), blk, 0, stream>>>(Qbuf, Kbuf, Vbuf, ctxb);

    o_gemm_kernel<<<dim3(8, 32), blk, 0, stream>>>(ctxb, owbf, o_b, (float*)d_out);
  } else {
    // ---- fallback: fp32-input reg-staged GEMMs
    const dim3 ggrid(8, 32);
    gemm_bt_kernel<false, 1><<<ggrid, blk, 0, stream>>>(query, q_w, q_b, Qbuf, QSCALE);
    gemm_bt_kernel<false, 1><<<ggrid, blk, 0, stream>>>(key, k_w, k_b, Kbuf, 1.0f);
    gemm_bt_kernel<false, 2><<<ggrid, blk, 0, stream>>>(value, v_w, v_b, Vbuf, 1.0f);
    attn_kernel<<<dim3(32, 32), blk, 0, stream>>>(Qbuf, Kbuf, Vbuf, ctxb);
    gemm_bt_kernel<true, 0><<<ggrid, blk, 0, stream>>>(ctxb, o_w, o_b, d_out, 1.0f);
  }
}

// Round 6
// 124.637 us; speedup vs baseline: 2.8200x; 1.1624x over previous
//
#include <hip/hip_runtime.h>
#include <hip/hip_bf16.h>

typedef __bf16 bf16;
typedef __attribute__((ext_vector_type(8))) __bf16 bf16x8;
typedef __attribute__((ext_vector_type(4))) __bf16 bf16x4;
typedef __attribute__((ext_vector_type(4))) float f32x4;

// ===========================================================================
// fp32 -> bf16 conversion pass (7 segments in one launch)
// ===========================================================================
struct CvtArgs {
  const float* src[7];
  bf16* dst[7];
  int n4[7];  // element count / 4
};

__global__ __launch_bounds__(256) void cvt_kernel(CvtArgs a) {
  const int seg = blockIdx.y;
  const float4* s = (const float4*)a.src[seg];
  bf16x4* d = (bf16x4*)a.dst[seg];
  const int n = a.n4[seg];
  const int stride = gridDim.x * 256;
  for (int i = blockIdx.x * 256 + threadIdx.x; i < n; i += stride) {
    const float4 v = s[i];
    bf16x4 h;
    h[0] = (bf16)v.x; h[1] = (bf16)v.y; h[2] = (bf16)v.z; h[3] = (bf16)v.w;
    d[i] = h;
  }
}

// ===========================================================================
// bf16 GEMM, counted-vmcnt triple-buffered pipeline.
// C[M,N] = (A[M,K] @ W[N,K]^T + bias) * scale ; M=4096, N=K=1024.
// BM=BN=128, BK=32, 4 waves (2x2), per-wave 64x64 output.
// 3 LDS buffers (48 KB -> 3 blocks/CU). Stage(t+2) issued each iteration;
// vmcnt never drains to 0 in the loop (T3/T4). T2 XOR swizzle (slot ^= row&3)
// applied on the global SOURCE of global_load_lds + on ds_read (rule 21).
// T5 setprio around the MFMA cluster. XCD chunk swizzle on block ids (T1).
// mode 0: fp32 [M,N]; mode 1: bf16 [B,H,S,hd]; mode 2: bf16 [B,H,hd,S] (V^T)
// ===========================================================================
__device__ __forceinline__ void gload16(const void* g, void* l) {
  __builtin_amdgcn_global_load_lds(
      (const __attribute__((address_space(1))) void*)g,
      (__attribute__((address_space(3))) void*)l, 16, 0, 0);
}

__device__ __forceinline__ void gemm_core2(const bf16* __restrict__ A,
                                           const bf16* __restrict__ W,
                                           const float* __restrict__ bias,
                                           void* __restrict__ C,
                                           float scale, int mode,
                                           int bx, int by) {
  constexpr int K = 1024, N = 1024, BK = 32, NT = K / BK;
  __shared__ __align__(16) bf16 As[3][128 * BK];
  __shared__ __align__(16) bf16 Bs[3][128 * BK];

  const int tid = threadIdx.x;
  const int lane = tid & 63;
  const int w = tid >> 6;
  const int wm = w >> 1, wn = w & 1;
  const int g = lane >> 4, c16 = lane & 15;
  const int row0 = by * 128;
  const int col0 = bx * 128;

  // staging geometry: round p covers rows p*64 + (tid>>2); dest linear tid*16B.
  // source col slot pre-swizzled by row&3 (involution; read applies same XOR).
  const int sr = tid >> 2;                          // 0..63
  const int ssw = ((tid & 3) ^ (sr & 3)) * 8;       // swizzled source col (elems)
  const int sdst = tid * 8;                         // dest offset (elems)

  // ds_read offsets (swizzled): slot g ^ (c16&3); rows wm*64+m*16+c16
  const int aoff = (wm * 64 + c16) * BK + ((g ^ (c16 & 3)) * 8);
  const int boff = (wn * 64 + c16) * BK + ((g ^ (c16 & 3)) * 8);

  f32x4 acc[4][4] = {};

#define STAGE2(buf, kt)                                                          \
  {                                                                              \
    const int k0_ = (kt)*BK;                                                     \
    gload16(&A[(size_t)(row0 + sr) * K + k0_ + ssw], &As[buf][sdst]);            \
    gload16(&A[(size_t)(row0 + 64 + sr) * K + k0_ + ssw], &As[buf][2048 + sdst]);\
    gload16(&W[(size_t)(col0 + sr) * K + k0_ + ssw], &Bs[buf][sdst]);            \
    gload16(&W[(size_t)(col0 + 64 + sr) * K + k0_ + ssw], &Bs[buf][2048 + sdst]);\
  }

  STAGE2(0, 0);
  STAGE2(1, 1);

  int cur = 0;
#pragma unroll 1
  for (int kt = 0; kt < NT; ++kt) {
    // wait: own stage(kt) complete (4 of stage(kt+1) may remain in flight)
    if (kt == NT - 1)
      asm volatile("s_waitcnt vmcnt(0)" ::: "memory");
    else
      asm volatile("s_waitcnt vmcnt(4)" ::: "memory");
    __builtin_amdgcn_s_barrier();       // buf[cur] block-wide resident;
    __builtin_amdgcn_sched_barrier(0);  // (and buf[(cur+2)%3] readers drained)

    if (kt + 2 < NT) {
      const int nb = (cur + 2 >= 3) ? cur - 1 : cur + 2;
      STAGE2(nb, kt + 2);  // 4 loads -> back to 8 in flight
    }

    bf16x8 a[4], b[4];
#pragma unroll
    for (int m = 0; m < 4; ++m) a[m] = *(const bf16x8*)&As[cur][aoff + m * 512];
#pragma unroll
    for (int n = 0; n < 4; ++n) b[n] = *(const bf16x8*)&Bs[cur][boff + n * 512];

    __builtin_amdgcn_s_setprio(1);
#pragma unroll
    for (int m = 0; m < 4; ++m)
#pragma unroll
      for (int n = 0; n < 4; ++n)
        acc[m][n] = __builtin_amdgcn_mfma_f32_16x16x32_bf16(a[m], b[n], acc[m][n], 0, 0, 0);
    __builtin_amdgcn_s_setprio(0);

    cur = (cur + 1 == 3) ? 0 : cur + 1;
  }
#undef STAGE2

  // ---- epilogue ----
#pragma unroll
  for (int m = 0; m < 4; ++m) {
#pragma unroll
    for (int n = 0; n < 4; ++n) {
      const int col = col0 + wn * 64 + n * 16 + c16;
      if (mode == 2) {
        const int row = row0 + wm * 64 + m * 16 + g * 4;  // s base, mult of 4
        const int bb = row >> 11, s = row & 2047;
        const int hh = col >> 6, j = col & 63;
        bf16x4 hv;
#pragma unroll
        for (int r = 0; r < 4; ++r)
          hv[r] = (bf16)((acc[m][n][r] + bias[col]) * scale);
        *(bf16x4*)&((bf16*)C)[(((size_t)bb * 16 + hh) * 64 + j) * 2048 + s] = hv;
      } else {
#pragma unroll
        for (int r = 0; r < 4; ++r) {
          const int row = row0 + wm * 64 + m * 16 + g * 4 + r;
          const float v = (acc[m][n][r] + bias[col]) * scale;
          if (mode == 1) {
            const int bb = row >> 11, s = row & 2047;
            const int hh = col >> 6, j = col & 63;
            ((bf16*)C)[(((size_t)bb * 16 + hh) * 2048 + s) * 64 + j] = (bf16)v;
          } else {
            ((float*)C)[(size_t)row * N + col] = v;
          }
        }
      }
    }
  }
}

// XCD chunk swizzle: nwg % 8 == 0 for all our grids (768, 256). nx=8, ny=32.
__device__ __forceinline__ void xcd_swz(int& bx, int& by, int& bz) {
  const int lid = ((int)blockIdx.z * 32 + (int)blockIdx.y) * 8 + (int)blockIdx.x;
  const int cpx = ((int)gridDim.z * 256) >> 3;
  int s = (lid & 7) * cpx + (lid >> 3);
  bx = s & 7;
  by = (s >> 3) & 31;
  bz = s >> 8;
}

__global__ __launch_bounds__(256, 3) void qkv_gemm_kernel(
    const bf16* __restrict__ qa, const bf16* __restrict__ ka, const bf16* __restrict__ va,
    const bf16* __restrict__ qw, const bf16* __restrict__ kw, const bf16* __restrict__ vw,
    const float* __restrict__ qb, const float* __restrict__ kb, const float* __restrict__ vb,
    bf16* __restrict__ Qo, bf16* __restrict__ Ko, bf16* __restrict__ Vo, float qscale) {
  int bx, by, bz;
  xcd_swz(bx, by, bz);
  const bf16* A = (bz == 0) ? qa : (bz == 1) ? ka : va;
  const bf16* W = (bz == 0) ? qw : (bz == 1) ? kw : vw;
  const float* bias = (bz == 0) ? qb : (bz == 1) ? kb : vb;
  bf16* C = (bz == 0) ? Qo : (bz == 1) ? Ko : Vo;
  const float scale = (bz == 0) ? qscale : 1.0f;
  const int mode = (bz == 2) ? 2 : 1;
  gemm_core2(A, W, bias, C, scale, mode, bx, by);
}

__global__ __launch_bounds__(256, 3) void o_gemm_kernel(
    const bf16* __restrict__ A, const bf16* __restrict__ W,
    const float* __restrict__ bias, float* __restrict__ C) {
  int bx, by, bz;
  xcd_swz(bx, by, bz);
  gemm_core2(A, W, bias, C, 1.0f, 0, bx, by);
}

// ===========================================================================
// Legacy fp32-input GEMM (fallback when ws too small for conversion buffers)
// ===========================================================================
template <bool A_BF16, int OUT_MODE>
__global__ __launch_bounds__(256) void gemm_bt_kernel(
    const void* __restrict__ Aptr, const float* __restrict__ Bt,
    const float* __restrict__ bias, void* __restrict__ Cptr, float scale) {
  constexpr int K = 1024, N = 1024;
  constexpr int BM = 128, BK = 32;
  constexpr int LSTR = BK + 8;
  __shared__ __align__(16) bf16 As[BM][LSTR];
  __shared__ __align__(16) bf16 Bs[BM][LSTR];

  const int tid = threadIdx.x;
  const int lane = tid & 63;
  const int w = tid >> 6;
  const int wr = w >> 1, wc = w & 1;
  const int g = lane >> 4, c16 = lane & 15;
  const int row0 = blockIdx.y * BM;
  const int col0 = blockIdx.x * BM;

  f32x4 acc[4][4] = {};

  for (int kt = 0; kt < K / BK; ++kt) {
    const int k0 = kt * BK;
    if constexpr (!A_BF16) {
      const float* A = (const float*)Aptr;
#pragma unroll
      for (int i = 0; i < 4; ++i) {
        const int r = (tid >> 3) + i * 32;
        const int c = (tid & 7) * 4;
        const float4 v = *(const float4*)(&A[(size_t)(row0 + r) * K + k0 + c]);
        bf16x4 hv;
        hv[0] = (bf16)v.x; hv[1] = (bf16)v.y; hv[2] = (bf16)v.z; hv[3] = (bf16)v.w;
        *(bf16x4*)&As[r][c] = hv;
      }
    } else {
      const bf16* A = (const bf16*)Aptr;
#pragma unroll
      for (int i = 0; i < 2; ++i) {
        const int r = (tid >> 2) + i * 64;
        const int c = (tid & 3) * 8;
        *(bf16x8*)&As[r][c] = *(const bf16x8*)(&A[(size_t)(row0 + r) * K + k0 + c]);
      }
    }
#pragma unroll
    for (int i = 0; i < 4; ++i) {
      const int r = (tid >> 3) + i * 32;
      const int c = (tid & 7) * 4;
      const float4 v = *(const float4*)(&Bt[(size_t)(col0 + r) * K + k0 + c]);
      bf16x4 hv;
      hv[0] = (bf16)v.x; hv[1] = (bf16)v.y; hv[2] = (bf16)v.z; hv[3] = (bf16)v.w;
      *(bf16x4*)&Bs[r][c] = hv;
    }
    __syncthreads();

    bf16x8 a[4], b[4];
#pragma unroll
    for (int m = 0; m < 4; ++m)
      a[m] = *(bf16x8*)&As[wr * 64 + m * 16 + c16][g * 8];
#pragma unroll
    for (int n = 0; n < 4; ++n)
      b[n] = *(bf16x8*)&Bs[wc * 64 + n * 16 + c16][g * 8];
#pragma unroll
    for (int m = 0; m < 4; ++m)
#pragma unroll
      for (int n = 0; n < 4; ++n)
        acc[m][n] = __builtin_amdgcn_mfma_f32_16x16x32_bf16(a[m], b[n], acc[m][n], 0, 0, 0);
    __syncthreads();
  }

#pragma unroll
  for (int m = 0; m < 4; ++m) {
#pragma unroll
    for (int n = 0; n < 4; ++n) {
      const int col = col0 + wc * 64 + n * 16 + c16;
      if constexpr (OUT_MODE == 2) {
        const int row = row0 + wr * 64 + m * 16 + g * 4;
        const int bb = row >> 11, s = row & 2047;
        const int hh = col >> 6, j = col & 63;
        bf16x4 hv;
#pragma unroll
        for (int r = 0; r < 4; ++r)
          hv[r] = (bf16)((acc[m][n][r] + bias[col]) * scale);
        *(bf16x4*)&((bf16*)Cptr)[(((size_t)bb * 16 + hh) * 64 + j) * 2048 + s] = hv;
      } else {
#pragma unroll
        for (int r = 0; r < 4; ++r) {
          const int row = row0 + wr * 64 + m * 16 + g * 4 + r;
          const float v = (acc[m][n][r] + bias[col]) * scale;
          if constexpr (OUT_MODE == 1) {
            const int bb = row >> 11, s = row & 2047;
            const int hh = col >> 6, j = col & 63;
            ((bf16*)Cptr)[(((size_t)bb * 16 + hh) * 2048 + s) * 64 + j] = (bf16)v;
          } else {
            ((float*)Cptr)[(size_t)row * N + col] = v;
          }
        }
      }
    }
  }
}

// ===========================================================================
// Causal flash attention, swapped-QK^T form (unchanged from round 5).
// ===========================================================================
__global__ __launch_bounds__(256) void attn_kernel(
    const bf16* __restrict__ Q, const bf16* __restrict__ Kb,
    const bf16* __restrict__ Vt, bf16* __restrict__ ctx) {
  constexpr int S = 2048, HD = 64, KVB = 64;
  constexpr int PS = 72;
  __shared__ __align__(16) bf16 Ks[KVB][PS];
  __shared__ __align__(16) bf16 Vs[HD][PS];
  __shared__ __align__(16) bf16 PT[4][16][PS];

  const int tid = threadIdx.x;
  const int lane = tid & 63;
  const int w = tid >> 6;
  const int g = lane >> 4, c16 = lane & 15;
  const int bh = blockIdx.x;
  const int b = bh >> 4, h = bh & 15;

  const int jj = blockIdx.y;
  const int sub = jj & 7, grp = jj >> 3;
  const int qt = (grp == 0) ? sub : (grp == 1) ? 31 - sub : (grp == 2) ? 8 + sub : 23 - sub;

  const bf16* Qh = Q + (size_t)bh * S * HD;
  const bf16* Kh = Kb + (size_t)bh * S * HD;
  const bf16* Vh = Vt + (size_t)bh * HD * S;

  const int srow = tid >> 2;
  const int scol = (tid & 3) * 16;

  const int q0w = qt * 64 + w * 16;
  const int nt = qt + 1;

  bf16x8 qf[2];
#pragma unroll
  for (int ks = 0; ks < 2; ++ks)
    qf[ks] = *(const bf16x8*)&Qh[(size_t)(q0w + c16) * HD + ks * 32 + g * 8];

  f32x4 oacc[4] = {};
  float m = -1e30f, l = 0.f;

  bf16x8 kr0 = *(const bf16x8*)&Kh[(size_t)srow * HD + scol];
  bf16x8 kr1 = *(const bf16x8*)&Kh[(size_t)srow * HD + scol + 8];
  bf16x8 vr0 = *(const bf16x8*)&Vh[(size_t)srow * S + scol];
  bf16x8 vr1 = *(const bf16x8*)&Vh[(size_t)srow * S + scol + 8];

#pragma unroll 1
  for (int kt = 0; kt < nt; ++kt) {
    __syncthreads();
    *(bf16x8*)&Ks[srow][scol] = kr0;
    *(bf16x8*)&Ks[srow][scol + 8] = kr1;
    *(bf16x8*)&Vs[srow][scol] = vr0;
    *(bf16x8*)&Vs[srow][scol + 8] = vr1;
    __syncthreads();

    const int kv0 = kt * KVB;
    const bool pf = (kt + 1 < nt);
    if (pf) {
      const int nkv = kv0 + KVB;
      kr0 = *(const bf16x8*)&Kh[(size_t)(nkv + srow) * HD + scol];
      kr1 = *(const bf16x8*)&Kh[(size_t)(nkv + srow) * HD + scol + 8];
      vr0 = *(const bf16x8*)&Vh[(size_t)srow * S + nkv + scol];
      vr1 = *(const bf16x8*)&Vh[(size_t)srow * S + nkv + scol + 8];
    }

    f32x4 sc[4] = {};
    __builtin_amdgcn_s_setprio(1);
#pragma unroll
    for (int ks = 0; ks < 2; ++ks) {
#pragma unroll
      for (int ni = 0; ni < 4; ++ni) {
        const bf16x8 kf = *(const bf16x8*)&Ks[ni * 16 + c16][ks * 32 + g * 8];
        sc[ni] = __builtin_amdgcn_mfma_f32_16x16x32_bf16(kf, qf[ks], sc[ni], 0, 0, 0);
      }
    }
    __builtin_amdgcn_s_setprio(0);

    if (kt == qt) {
      const int qq = q0w + c16;
#pragma unroll
      for (int ni = 0; ni < 4; ++ni)
#pragma unroll
        for (int r = 0; r < 4; ++r) {
          const int kv = kv0 + ni * 16 + g * 4 + r;
          if (kv > qq) sc[ni][r] = -1e30f;
        }
    }

    float t = -1e30f;
#pragma unroll
    for (int ni = 0; ni < 4; ++ni)
#pragma unroll
      for (int r = 0; r < 4; ++r) t = fmaxf(t, sc[ni][r]);
    t = fmaxf(t, __shfl_xor(t, 16));
    t = fmaxf(t, __shfl_xor(t, 32));
    if (!__all(t <= m + 8.0f)) {
      const float mnew = fmaxf(m, t);
      const float corr = exp2f(m - mnew);
      m = mnew;
      l *= corr;
      float cb[4];
#pragma unroll
      for (int r = 0; r < 4; ++r)
        cb[r] = __shfl(corr, (lane & 48) + g * 4 + r);
#pragma unroll
      for (int nd = 0; nd < 4; ++nd)
#pragma unroll
        for (int r = 0; r < 4; ++r) oacc[nd][r] *= cb[r];
    }
    float rs = 0.f;
#pragma unroll
    for (int ni = 0; ni < 4; ++ni)
#pragma unroll
      for (int r = 0; r < 4; ++r) {
        sc[ni][r] = exp2f(sc[ni][r] - m);
        rs += sc[ni][r];
      }
    rs += __shfl_xor(rs, 16);
    rs += __shfl_xor(rs, 32);
    l += rs;

#pragma unroll
    for (int ni = 0; ni < 4; ++ni) {
      bf16x4 hv;
#pragma unroll
      for (int r = 0; r < 4; ++r) hv[r] = (bf16)sc[ni][r];
      *(bf16x4*)&PT[w][c16][ni * 16 + g * 4] = hv;
    }

    __builtin_amdgcn_s_setprio(1);
#pragma unroll
    for (int ks = 0; ks < 2; ++ks) {
      const bf16x8 pa = *(const bf16x8*)&PT[w][c16][ks * 32 + g * 8];
#pragma unroll
      for (int nd = 0; nd < 4; ++nd) {
        const bf16x8 bv = *(const bf16x8*)&Vs[nd * 16 + c16][ks * 32 + g * 8];
        oacc[nd] = __builtin_amdgcn_mfma_f32_16x16x32_bf16(pa, bv, oacc[nd], 0, 0, 0);
      }
    }
    __builtin_amdgcn_s_setprio(0);
  }

  float lb[4];
#pragma unroll
  for (int r = 0; r < 4; ++r)
    lb[r] = __shfl(l, (lane & 48) + g * 4 + r);
#pragma unroll
  for (int nd = 0; nd < 4; ++nd)
#pragma unroll
    for (int r = 0; r < 4; ++r) {
      const int q = q0w + g * 4 + r;
      const int col = h * 64 + nd * 16 + c16;
      ctx[((size_t)b * S + q) * 1024 + col] = (bf16)(oacc[nd][r] / lb[r]);
    }
}

// ===========================================================================
extern "C" void kernel_launch(void* const* d_in, const int* in_sizes, int n_in,
                              void* d_out, int out_size, void* d_ws, size_t ws_size,
                              hipStream_t stream) {
  (void)in_sizes; (void)n_in; (void)out_size;
  const float* query = (const float*)d_in[0];
  const float* key   = (const float*)d_in[1];
  const float* value = (const float*)d_in[2];
  // d_in[3] = attn_mask (causal triu) — structural, not read
  const float* q_w = (const float*)d_in[4];
  const float* q_b = (const float*)d_in[5];
  const float* k_w = (const float*)d_in[6];
  const float* k_b = (const float*)d_in[7];
  const float* v_w = (const float*)d_in[8];
  const float* v_b = (const float*)d_in[9];
  const float* o_w = (const float*)d_in[10];
  const float* o_b = (const float*)d_in[11];

  const size_t NELEM = (size_t)4096 * 1024;  // B*S*D
  const size_t WELEM = (size_t)1024 * 1024;
  bf16* Qbuf = (bf16*)d_ws;        //  0 MB
  bf16* Kbuf = Qbuf + NELEM;       //  8 MB
  bf16* Vbuf = Kbuf + NELEM;       // 16 MB  [B,H,hd,S]
  bf16* ctxb = Vbuf + NELEM;       // 24 MB

  const dim3 blk(256);
  const float QSCALE = 0.125f * 1.44269504088896f;  // 1/sqrt(64) * log2(e)

  const size_t need = 64ull * 1024 * 1024;
  if (ws_size >= need) {
    // ---- fast path: pre-convert everything to bf16, pipelined GEMMs
    bf16* qbf  = ctxb + NELEM;       // 32 MB
    bf16* kbf  = qbf + NELEM;        // 40 MB
    bf16* vbf  = kbf + NELEM;        // 48 MB
    bf16* qwbf = vbf + NELEM;        // 56 MB
    bf16* kwbf = qwbf + WELEM;       // 58 MB
    bf16* vwbf = kwbf + WELEM;       // 60 MB
    bf16* owbf = vwbf + WELEM;       // 62 MB .. 64 MB

    CvtArgs ca;
    ca.src[0] = query; ca.dst[0] = qbf;  ca.n4[0] = (int)(NELEM / 4);
    ca.src[1] = key;   ca.dst[1] = kbf;  ca.n4[1] = (int)(NELEM / 4);
    ca.src[2] = value; ca.dst[2] = vbf;  ca.n4[2] = (int)(NELEM / 4);
    ca.src[3] = q_w;   ca.dst[3] = qwbf; ca.n4[3] = (int)(WELEM / 4);
    ca.src[4] = k_w;   ca.dst[4] = kwbf; ca.n4[4] = (int)(WELEM / 4);
    ca.src[5] = v_w;   ca.dst[5] = vwbf; ca.n4[5] = (int)(WELEM / 4);
    ca.src[6] = o_w;   ca.dst[6] = owbf; ca.n4[6] = (int)(WELEM / 4);
    cvt_kernel<<<dim3(256, 7), blk, 0, stream>>>(ca);

    qkv_gemm_kernel<<<dim3(8, 32, 3), blk, 0, stream>>>(
        qbf, kbf, vbf, qwbf, kwbf, vwbf, q_b, k_b, v_b, Qbuf, Kbuf, Vbuf, QSCALE);

    attn_kernel<<<dim3(32, 32), blk, 0, stream>>>(Qbuf, Kbuf, Vbuf, ctxb);

    o_gemm_kernel<<<dim3(8, 32), blk, 0, stream>>>(ctxb, owbf, o_b, (float*)d_out);
  } else {
    // ---- fallback: fp32-input reg-staged GEMMs
    const dim3 ggrid(8, 32);
    gemm_bt_kernel<false, 1><<<ggrid, blk, 0, stream>>>(query, q_w, q_b, Qbuf, QSCALE);
    gemm_bt_kernel<false, 1><<<ggrid, blk, 0, stream>>>(key, k_w, k_b, Kbuf, 1.0f);
    gemm_bt_kernel<false, 2><<<ggrid, blk, 0, stream>>>(value, v_w, v_b, Vbuf, 1.0f);
    attn_kernel<<<dim3(32, 32), blk, 0, stream>>>(Qbuf, Kbuf, Vbuf, ctxb);
    gemm_bt_kernel<true, 0><<<ggrid, blk, 0, stream>>>(ctxb, o_w, o_b, d_out, 1.0f);
  }
}